// Round 1
// 1119.102 us; speedup vs baseline: 1.1273x; 1.1273x over previous
//
#include <hip/hip_runtime.h>
#include <hip/hip_bf16.h>

// ---- problem constants ----
#define HH 12
#define DD 128
#define EE 1536
#define QKVP 4608       // fused q|k|v row pitch (shorts)
#define NBATCH 8
#define SEQ 3072
#define NBLK 256        // SEQ / CHK
#define CHK 12
#define CTXW 24
#define MTOK 24576      // NBATCH * SEQ

#define Q_SCALE_BASE 0.12751743f   // D^-0.5 / ln2
#define K_SCALE_F 1.8946361322f    // ln(1+e) / ln2

#define PITCH 65        // LDS row pitch in 4B words (odd -> bank stride 1, conflict-free)

typedef short s16x8 __attribute__((ext_vector_type(8)));
typedef float f32x4 __attribute__((ext_vector_type(4)));

__device__ __forceinline__ float bf2f(unsigned short u) {
  return __builtin_bit_cast(float, ((unsigned int)u) << 16);
}
__device__ __forceinline__ unsigned short f2bf(float f) {
  unsigned int u = __builtin_bit_cast(unsigned int, f);
  u += 0x7fffu + ((u >> 16) & 1u);   // round-to-nearest-even
  return (unsigned short)(u >> 16);
}
__device__ __forceinline__ void bf2f2(unsigned int u, float& lo, float& hi) {
  lo = __builtin_bit_cast(float, u << 16);
  hi = __builtin_bit_cast(float, u & 0xffff0000u);
}

// async global->LDS, 16B per lane; lds dest must be wave-uniform base (lands at base + lane*16)
__device__ __forceinline__ void async16(const void* g, void* l) {
  __builtin_amdgcn_global_load_lds(
      (const __attribute__((address_space(1))) unsigned int*)g,
      (__attribute__((address_space(3))) unsigned int*)l, 16, 0, 0);
}

// ---- fp32 -> bf16 convert (vectorized) ----
__global__ __launch_bounds__(256) void k_cvt(const float4* __restrict__ in,
                                             ushort4* __restrict__ out, int n4) {
  int i = blockIdx.x * 256 + threadIdx.x;
  if (i < n4) {
    float4 v = in[i];
    ushort4 o;
    o.x = f2bf(v.x); o.y = f2bf(v.y); o.z = f2bf(v.z); o.w = f2bf(v.w);
    out[i] = o;
  }
}

// ---- per-dim query scale: Q_SCALE * softplus(per_dim_scale) ----
__global__ void k_qscale(const float* __restrict__ pds, float* __restrict__ qs) {
  int d = threadIdx.x;
  if (d < DD) {
    float x = pds[d];
    float sp = (x > 20.f) ? x : log1pf(expf(x));
    qs[d] = Q_SCALE_BASE * sp;
  }
}

// ---- rel_k = pos_emb @ w_rel.T  -> bf16 [CTXW][EE] ----
__global__ __launch_bounds__(256) void k_rel(const float* __restrict__ pos,
                                             const float* __restrict__ w_rel,
                                             unsigned short* __restrict__ rel16) {
  __shared__ unsigned short lp[12 * EE];
  const int t = threadIdx.x;
  const int p0 = blockIdx.y * 12;
  for (int i = t; i < 12 * EE / 4; i += 256) {
    float4 x = ((const float4*)(pos + (long)p0 * EE))[i];
    ushort4 o; o.x = f2bf(x.x); o.y = f2bf(x.y); o.z = f2bf(x.z); o.w = f2bf(x.w);
    ((ushort4*)lp)[i] = o;
  }
  __syncthreads();
  const int col = blockIdx.x * 128 + (t & 127);
  const int pg = t >> 7;  // 0 or 1 -> 6 p-rows each
  float acc[6] = {0.f, 0.f, 0.f, 0.f, 0.f, 0.f};
  const float* wr = w_rel + (long)col * EE;
  for (int e = 0; e < EE; ++e) {
    float w = wr[e];
#pragma unroll
    for (int i = 0; i < 6; ++i) acc[i] += w * bf2f(lp[(pg * 6 + i) * EE + e]);
  }
#pragma unroll
  for (int i = 0; i < 6; ++i)
    rel16[(long)(p0 + pg * 6 + i) * EE + col] = f2bf(acc[i]);
}

// =====================================================================
// 256x256 8-phase bf16 MFMA GEMM (learn_hip m201 template, plain HIP)
// C[M,N] = A[M,K] * Bt[N,K]^T.  BK=64, 512 threads = 8 waves (2M x 4N),
// per-wave 128x64 output (acc[8][4]), 128 KiB double-buffered LDS.
// LDS swizzle: logical k-granule g stored at g ^ (row&7) (16B granules),
// realized as linear LDS dest + permuted GLOBAL source (rule #21), and
// the same XOR applied on ds_read addresses.
// Counted vmcnt(2) once per K-tile; raw s_barrier (no vmcnt(0) drain);
// setprio(1) around each 16-MFMA cluster.
// =====================================================================

// stage one 128x64-bf16 half-tile: 8 waves x 2 global_load_lds (2 loads/wave)
// g0 points at (row0, k0) element of the half-tile; lhalf = LDS base (shorts).
__device__ __forceinline__ void stage_half(const unsigned short* g0, long Kl,
                                           unsigned short* lhalf,
                                           int w, int rlo, int qz) {
  const unsigned short* s0 = g0 + (long)(w * 16 + rlo) * Kl + qz * 8;
  async16(s0,          lhalf + w * 1024);        // rows w*16 .. +7
  async16(s0 + 8 * Kl, lhalf + w * 1024 + 512);  // rows w*16+8 .. +15
}

__device__ __forceinline__ void tile4(
    unsigned short* AP, unsigned short* BP,        // current buffer (tile t)
    unsigned short* AQ, unsigned short* BQ,        // other buffer (tile t+1)
    const unsigned short* gAt, const unsigned short* gBt, long Kl,
    int t1, int t2, int w, int rlo, int qz,
    int aBase, int bBase, int sw0, int sw1, f32x4 (&acc)[8][4]) {
  s16x8 af[4], bf[4];

  // ---- P1: a(m0-3,ks0) + b(ks0); stage B-hi(t1) -> BQ+8192 ----
#pragma unroll
  for (int i = 0; i < 4; ++i) af[i] = *(const s16x8*)&AP[(aBase + 16 * i) * 64 + sw0];
#pragma unroll
  for (int j = 0; j < 4; ++j) bf[j] = *(const s16x8*)&BP[(bBase + 16 * j) * 64 + sw0];
  stage_half(gBt + 128 * Kl + (long)t1 * 64, Kl, BQ + 8192, w, rlo, qz);
  __builtin_amdgcn_s_barrier();
  __builtin_amdgcn_s_setprio(1);
#pragma unroll
  for (int i = 0; i < 4; ++i)
#pragma unroll
    for (int j = 0; j < 4; ++j)
      acc[i][j] = __builtin_amdgcn_mfma_f32_16x16x32_bf16(af[i], bf[j], acc[i][j], 0, 0, 0);
  __builtin_amdgcn_s_setprio(0);
  __builtin_amdgcn_s_barrier();

  // ---- P2: a(m4-7,ks0); stage A-lo(t1) -> AQ ----
#pragma unroll
  for (int i = 0; i < 4; ++i) af[i] = *(const s16x8*)&AP[(aBase + 64 + 16 * i) * 64 + sw0];
  stage_half(gAt + (long)t1 * 64, Kl, AQ, w, rlo, qz);
  __builtin_amdgcn_s_barrier();
  __builtin_amdgcn_s_setprio(1);
#pragma unroll
  for (int i = 0; i < 4; ++i)
#pragma unroll
    for (int j = 0; j < 4; ++j)
      acc[4 + i][j] = __builtin_amdgcn_mfma_f32_16x16x32_bf16(af[i], bf[j], acc[4 + i][j], 0, 0, 0);
  __builtin_amdgcn_s_setprio(0);
  __builtin_amdgcn_s_barrier();

  // ---- P3: a(m0-3,ks1) + b(ks1); stage A-hi(t1) -> AQ+8192 ----
#pragma unroll
  for (int i = 0; i < 4; ++i) af[i] = *(const s16x8*)&AP[(aBase + 16 * i) * 64 + sw1];
#pragma unroll
  for (int j = 0; j < 4; ++j) bf[j] = *(const s16x8*)&BP[(bBase + 16 * j) * 64 + sw1];
  stage_half(gAt + 128 * Kl + (long)t1 * 64, Kl, AQ + 8192, w, rlo, qz);
  __builtin_amdgcn_s_barrier();
  __builtin_amdgcn_s_setprio(1);
#pragma unroll
  for (int i = 0; i < 4; ++i)
#pragma unroll
    for (int j = 0; j < 4; ++j)
      acc[i][j] = __builtin_amdgcn_mfma_f32_16x16x32_bf16(af[i], bf[j], acc[i][j], 0, 0, 0);
  __builtin_amdgcn_s_setprio(0);
  __builtin_amdgcn_s_barrier();

  // ---- P4: a(m4-7,ks1); stage B-lo(t2) -> BP; counted vmcnt ----
#pragma unroll
  for (int i = 0; i < 4; ++i) af[i] = *(const s16x8*)&AP[(aBase + 64 + 16 * i) * 64 + sw1];
  stage_half(gBt + (long)t2 * 64, Kl, BP, w, rlo, qz);
  // all 8 loads of tile t1 are older than the 2 just issued -> vmcnt(2)
  asm volatile("s_waitcnt vmcnt(2)" ::: "memory");
  __builtin_amdgcn_s_barrier();
  __builtin_amdgcn_s_setprio(1);
#pragma unroll
  for (int i = 0; i < 4; ++i)
#pragma unroll
    for (int j = 0; j < 4; ++j)
      acc[4 + i][j] = __builtin_amdgcn_mfma_f32_16x16x32_bf16(af[i], bf[j], acc[4 + i][j], 0, 0, 0);
  __builtin_amdgcn_s_setprio(0);
  __builtin_amdgcn_s_barrier();
}

__global__ __launch_bounds__(512, 2) void k_gemm256(
    const unsigned short* __restrict__ A, const unsigned short* __restrict__ Bt,
    void* __restrict__ Cv, int M, int N, int K, int gN,
    int mode, const float* __restrict__ qscale, int c_f32) {
  __shared__ unsigned short sm[65536];   // 128 KiB: A0|B0|A1|B1, 16384 shorts each

  const int tid = threadIdx.x;
  const int w = tid >> 6;
  const int lane = tid & 63;
  const int quad = lane >> 4;
  const int l16 = lane & 15;
  const int sw = l16 & 7;
  const int rlo = lane >> 3;             // staging: row-within-8 for this lane
  const int qz = (lane & 7) ^ rlo;       // staging: inverse-swizzled source granule

  // XCD-aware bijective block swizzle (nwg % 8 == 0 in our launches),
  // n-fastest within an XCD chunk -> A-panel (768 KB) reused from XCD L2.
  const int nwg = gridDim.x;
  const int orig = blockIdx.x;
  const int qd = nwg >> 3;
  const int wg = (orig & 7) * qd + (orig >> 3);
  const int mt = wg / gN, nt = wg - mt * gN;
  const long bm = (long)mt * 256, bn = (long)nt * 256;
  const long Kl = K;
  const unsigned short* gAt = A + bm * Kl;
  const unsigned short* gBt = Bt + bn * Kl;

  unsigned short* A0 = sm;
  unsigned short* B0 = sm + 16384;
  unsigned short* A1 = sm + 32768;
  unsigned short* B1 = sm + 49152;

  const int aBase = (w >> 2) * 128 + l16;            // wave M-panel row base
  const int bBase = (w & 3) * 64 + l16;              // wave N-panel row base
  const int sw0 = ((quad ^ sw) & 7) * 8;             // ks=0 swizzled granule offset (shorts)
  const int sw1 = (((4 | quad) ^ sw) & 7) * 8;       // ks=1

  f32x4 acc[8][4] = {};
  const int NT = K >> 6;                             // K-tiles of 64 (even)

  // ---- prologue: tile0 fully -> buf0; B-lo(tile1) -> buf1 ----
  stage_half(gBt,            Kl, B0,        w, rlo, qz);
  stage_half(gBt + 128 * Kl, Kl, B0 + 8192, w, rlo, qz);
  stage_half(gAt,            Kl, A0,        w, rlo, qz);
  stage_half(gAt + 128 * Kl, Kl, A0 + 8192, w, rlo, qz);
  stage_half(gBt + 64,       Kl, B1,        w, rlo, qz);
  asm volatile("s_waitcnt vmcnt(2)" ::: "memory");   // tile0's 8 loads retired
  __builtin_amdgcn_s_barrier();

  for (int t = 0; t < NT; t += 2) {
    const int t2 = (t + 2 == NT) ? 0 : t + 2;                 // wrap: dead re-stage, no OOB
    const int u2 = (t + 3 >= NT) ? t + 3 - NT : t + 3;
    tile4(A0, B0, A1, B1, gAt, gBt, Kl, t + 1, t2, w, rlo, qz, aBase, bBase, sw0, sw1, acc);
    tile4(A1, B1, A0, B0, gAt, gBt, Kl, t2,    u2, w, rlo, qz, aBase, bBase, sw0, sw1, acc);
  }

  // ---- epilogue: C/D layout col=lane&15, row=quad*4+reg ----
  const int wmq = (w >> 2) * 128;
  const int wnq = (w & 3) * 64;
#pragma unroll
  for (int j = 0; j < 4; ++j) {
    const long col = bn + wnq + 16 * j + l16;
    float scale = 1.0f;
    if (mode == 3)
      scale = (col < 1536) ? qscale[col & (DD - 1)] : (col < 3072 ? K_SCALE_F : 1.0f);
#pragma unroll
    for (int i = 0; i < 8; ++i) {
      const long row0 = bm + wmq + 16 * i + quad * 4;
#pragma unroll
      for (int r = 0; r < 4; ++r) {
        float vv = acc[i][j][r] * scale;
        if (c_f32) ((float*)Cv)[(row0 + r) * (long)N + col] = vv;
        else ((unsigned short*)Cv)[(row0 + r) * (long)N + col] = f2bf(vv);
      }
    }
  }
}

// ---- chunked local attention, one block per (b, n, h) ----
// LDS pitch 65 words -> conflict-free score/output phases.
__global__ __launch_bounds__(256) void k_attn(
    const unsigned short* __restrict__ qkv, const unsigned short* __restrict__ rel,
    unsigned short* __restrict__ attn_out, float* __restrict__ aw_out) {
  const int n = blockIdx.x;
  const int b = blockIdx.y;
  const int h = blockIdx.z;
  const int t = threadIdx.x;

  __shared__ unsigned int lq[CHK * PITCH];
  __shared__ unsigned int lk[CTXW * PITCH];
  __shared__ unsigned int lv[CTXW * PITCH];
  __shared__ unsigned int lr[CTXW * PITCH];
  __shared__ float sac[CHK * CTXW];
  __shared__ float sbd[CHK * CTXW];
  __shared__ float smax[CHK];
  __shared__ float sinv[CHK];

  const long tok0 = (long)b * SEQ + (long)n * CHK;
  const long hq = (long)h * DD;

  // ---- stage q: 12 rows x 16 uint4 ----
  for (int u = t; u < CHK * 16; u += 256) {
    int r = u >> 4, w4 = u & 15;
    uint4 x = *(const uint4*)&qkv[(tok0 + r) * QKVP + hq + w4 * 8];
    unsigned int* d = &lq[r * PITCH + w4 * 4];
    d[0] = x.x; d[1] = x.y; d[2] = x.z; d[3] = x.w;
  }
  // ---- stage k, v (with left halo), rel: 24 rows x 16 uint4 each ----
  for (int u = t; u < CTXW * 16; u += 256) {
    int r = u >> 4, w4 = u & 15;
    int s = n * CHK + r - 12;
    uint4 kx, vx;
    if (s >= 0) {
      const unsigned short* base = &qkv[((long)b * SEQ + s) * QKVP + hq];
      kx = *(const uint4*)&base[1536 + w4 * 8];
      vx = *(const uint4*)&base[3072 + w4 * 8];
    } else {
      kx = make_uint4(0, 0, 0, 0);
      vx = make_uint4(0, 0, 0, 0);
    }
    uint4 rx = *(const uint4*)&rel[(long)r * EE + hq + w4 * 8];
    unsigned int* dk = &lk[r * PITCH + w4 * 4];
    unsigned int* dv = &lv[r * PITCH + w4 * 4];
    unsigned int* dr = &lr[r * PITCH + w4 * 4];
    dk[0] = kx.x; dk[1] = kx.y; dk[2] = kx.z; dk[3] = kx.w;
    dv[0] = vx.x; dv[1] = vx.y; dv[2] = vx.z; dv[3] = vx.w;
    dr[0] = rx.x; dr[1] = rx.y; dr[2] = rx.z; dr[3] = rx.w;
  }
  __syncthreads();

  // ---- scores: 288 (c,j) pairs, dot over 64 dwords (conflict-free banks) ----
  for (int p = t; p < CHK * CTXW; p += 256) {
    int c = p / CTXW, j = p - c * CTXW;
    const unsigned int* uq = &lq[c * PITCH];
    const unsigned int* uk = &lk[j * PITCH];
    const unsigned int* ur = &lr[j * PITCH];
    float ac = 0.f, bd = 0.f;
#pragma unroll 16
    for (int d2 = 0; d2 < DD / 2; ++d2) {
      float a0, a1, k0f, k1f, r0, r1;
      bf2f2(uq[d2], a0, a1);
      bf2f2(uk[d2], k0f, k1f);
      bf2f2(ur[d2], r0, r1);
      ac += a0 * k0f + a1 * k1f;
      bd += a0 * r0 + a1 * r1;
    }
    sac[p] = ac;
    sbd[p] = bd;
  }
  __syncthreads();

  // ---- rel-shift + softcap (parallel over 288) ----
  for (int p = t; p < CHK * CTXW; p += 256) {
    int c = p / CTXW, j = p - c * CTXW;
    float y;
    if (j >= c) y = sbd[c * CTXW + (j - c)];
    else if (j == c - 1) y = 0.f;
    else y = sbd[(c - 1) * CTXW + (j - c + CTXW + 1)];
    float x = (sac[p] + y) * 0.02f;
    x = fminf(fmaxf(x, -15.f), 15.f);
    float e2 = __expf(2.f * x);
    sac[p] = 50.f * (e2 - 1.f) / (e2 + 1.f);   // 50*tanh(x)
  }
  __syncthreads();

  // ---- row max ----
  if (t < CHK) {
    float m = -3.0e38f;
#pragma unroll
    for (int j = 0; j < CTXW; ++j) m = fmaxf(m, sac[t * CTXW + j]);
    smax[t] = m;
  }
  __syncthreads();

  // ---- exp (parallel) ----
  for (int p = t; p < CHK * CTXW; p += 256) {
    int c = p / CTXW;
    sbd[p] = __expf(sac[p] - smax[c]);
  }
  __syncthreads();

  // ---- row sum ----
  if (t < CHK) {
    float s = 0.f;
#pragma unroll
    for (int j = 0; j < CTXW; ++j) s += sbd[t * CTXW + j];
    sinv[t] = 1.f / s;
  }
  __syncthreads();

  // ---- normalize + write attn_weights ----
  for (int p = t; p < CHK * CTXW; p += 256) {
    int c = p / CTXW, j = p - c * CTXW;
    float w = sbd[p] * sinv[c];
    sac[p] = w;
    aw_out[((((long)b * HH + h) * NBLK + n) * CHK + c) * CTXW + j] = w;
  }
  __syncthreads();

  // ---- output: O[c][d] = sum_j w[c][j] * v[j][d], dword-paired d ----
  for (int p = t; p < CHK * (DD / 2); p += 256) {
    int c = p >> 6, d2 = p & 63;
    float a0 = 0.f, a1 = 0.f;
#pragma unroll
    for (int j = 0; j < CTXW; ++j) {
      float w = sac[c * CTXW + j];
      float v0, v1;
      bf2f2(lv[j * PITCH + d2], v0, v1);
      a0 += w * v0; a1 += w * v1;
    }
    unsigned int packed = ((unsigned int)f2bf(a1) << 16) | (unsigned int)f2bf(a0);
    *(unsigned int*)&attn_out[(tok0 + c) * EE + hq + d2 * 2] = packed;
  }
}

extern "C" void kernel_launch(void* const* d_in, const int* in_sizes, int n_in,
                              void* d_out, int out_size, void* d_ws, size_t ws_size,
                              hipStream_t stream) {
  const float* hs     = (const float*)d_in[0];
  const float* pos    = (const float*)d_in[1];
  const float* w_q    = (const float*)d_in[2];
  const float* w_k    = (const float*)d_in[3];
  const float* w_v    = (const float*)d_in[4];
  const float* w_post = (const float*)d_in[5];
  const float* w_rel  = (const float*)d_in[6];
  const float* pds    = (const float*)d_in[7];

  char* ws = (char*)d_ws;
  const size_t TOKB = (size_t)MTOK * EE * 2;        // bytes per [MTOK,EE] bf16
  const size_t WB   = (size_t)EE * EE * 2;
  unsigned short* hs16   = (unsigned short*)(ws);
  unsigned short* qkv16  = (unsigned short*)(ws + TOKB);           // [MTOK][4608]
  unsigned short* wq16   = (unsigned short*)(ws + 4 * TOKB);       // wq|wk|wv contiguous
  unsigned short* wk16   = (unsigned short*)(ws + 4 * TOKB + WB);
  unsigned short* wv16   = (unsigned short*)(ws + 4 * TOKB + 2 * WB);
  unsigned short* wp16   = (unsigned short*)(ws + 4 * TOKB + 3 * WB);
  unsigned short* rel16  = (unsigned short*)(ws + 4 * TOKB + 4 * WB);
  float* qscale          = (float*)(ws + 4 * TOKB + 4 * WB + CTXW * EE * 2);
  unsigned short* attn16 = hs16;  // hs16 dead after qkv GEMM

  float* out = (float*)d_out;
  float* aw  = out + (size_t)MTOK * EE;

  // bf16 conversions
  k_cvt<<<36864, 256, 0, stream>>>((const float4*)hs, (ushort4*)hs16, MTOK * EE / 4);
  k_cvt<<<2304, 256, 0, stream>>>((const float4*)w_q, (ushort4*)wq16, EE * EE / 4);
  k_cvt<<<2304, 256, 0, stream>>>((const float4*)w_k, (ushort4*)wk16, EE * EE / 4);
  k_cvt<<<2304, 256, 0, stream>>>((const float4*)w_v, (ushort4*)wv16, EE * EE / 4);
  k_cvt<<<2304, 256, 0, stream>>>((const float4*)w_post, (ushort4*)wp16, EE * EE / 4);
  k_qscale<<<1, 128, 0, stream>>>(pds, qscale);
  k_rel<<<dim3(12, 2), 256, 0, stream>>>(pos, w_rel, rel16);

  // fused q|k|v projection: Bt = [wq;wk;wv] (contiguous), N=4608, scales in epilogue
  k_gemm256<<<dim3((MTOK / 256) * (QKVP / 256)), 512, 0, stream>>>(
      hs16, wq16, qkv16, MTOK, QKVP, EE, QKVP / 256, 3, qscale, 0);

  // attention: one block per (b, n, h)
  k_attn<<<dim3(NBLK, NBATCH, HH), 256, 0, stream>>>(qkv16, rel16, attn16, aw);

  // output projection -> fp32 d_out
  k_gemm256<<<dim3((MTOK / 256) * (EE / 256)), 512, 0, stream>>>(
      attn16, wp16, out, MTOK, EE, EE, EE / 256, 0, nullptr, 1);
}

// Round 2
// 1033.156 us; speedup vs baseline: 1.2210x; 1.0832x over previous
//
#include <hip/hip_runtime.h>
#include <hip/hip_bf16.h>

// ---- problem constants ----
#define HH 12
#define DD 128
#define EE 1536
#define QKVP 4608       // fused q|k|v row pitch (shorts)
#define NBATCH 8
#define SEQ 3072
#define NBLK 256        // SEQ / CHK
#define CHK 12
#define CTXW 24
#define MTOK 24576      // NBATCH * SEQ

#define Q_SCALE_BASE 0.12751743f   // D^-0.5 / ln2
#define K_SCALE_F 1.8946361322f    // ln(1+e) / ln2

#define PITCH 65        // LDS row pitch in 4B words (odd -> bank stride 1, conflict-free)

typedef short s16x8 __attribute__((ext_vector_type(8)));
typedef float f32x4 __attribute__((ext_vector_type(4)));

__device__ __forceinline__ float bf2f(unsigned short u) {
  return __builtin_bit_cast(float, ((unsigned int)u) << 16);
}
__device__ __forceinline__ unsigned short f2bf(float f) {
  unsigned int u = __builtin_bit_cast(unsigned int, f);
  u += 0x7fffu + ((u >> 16) & 1u);   // round-to-nearest-even
  return (unsigned short)(u >> 16);
}
__device__ __forceinline__ void bf2f2(unsigned int u, float& lo, float& hi) {
  lo = __builtin_bit_cast(float, u << 16);
  hi = __builtin_bit_cast(float, u & 0xffff0000u);
}

// async global->LDS, 16B per lane; lds dest must be wave-uniform base (lands at base + lane*16)
__device__ __forceinline__ void async16(const void* g, void* l) {
  __builtin_amdgcn_global_load_lds(
      (const __attribute__((address_space(1))) unsigned int*)g,
      (__attribute__((address_space(3))) unsigned int*)l, 16, 0, 0);
}

// ---- fp32 -> bf16 convert (vectorized) ----
__global__ __launch_bounds__(256) void k_cvt(const float4* __restrict__ in,
                                             ushort4* __restrict__ out, int n4) {
  int i = blockIdx.x * 256 + threadIdx.x;
  if (i < n4) {
    float4 v = in[i];
    ushort4 o;
    o.x = f2bf(v.x); o.y = f2bf(v.y); o.z = f2bf(v.z); o.w = f2bf(v.w);
    out[i] = o;
  }
}

// ---- per-dim query scale: Q_SCALE * softplus(per_dim_scale) ----
__global__ void k_qscale(const float* __restrict__ pds, float* __restrict__ qs) {
  int d = threadIdx.x;
  if (d < DD) {
    float x = pds[d];
    float sp = (x > 20.f) ? x : log1pf(expf(x));
    qs[d] = Q_SCALE_BASE * sp;
  }
}

// ---- rel_k = pos_emb @ w_rel.T  -> bf16 [CTXW][EE] ----
__global__ __launch_bounds__(256) void k_rel(const float* __restrict__ pos,
                                             const float* __restrict__ w_rel,
                                             unsigned short* __restrict__ rel16) {
  __shared__ unsigned short lp[12 * EE];
  const int t = threadIdx.x;
  const int p0 = blockIdx.y * 12;
  for (int i = t; i < 12 * EE / 4; i += 256) {
    float4 x = ((const float4*)(pos + (long)p0 * EE))[i];
    ushort4 o; o.x = f2bf(x.x); o.y = f2bf(x.y); o.z = f2bf(x.z); o.w = f2bf(x.w);
    ((ushort4*)lp)[i] = o;
  }
  __syncthreads();
  const int col = blockIdx.x * 128 + (t & 127);
  const int pg = t >> 7;  // 0 or 1 -> 6 p-rows each
  float acc[6] = {0.f, 0.f, 0.f, 0.f, 0.f, 0.f};
  const float* wr = w_rel + (long)col * EE;
  for (int e = 0; e < EE; ++e) {
    float w = wr[e];
#pragma unroll
    for (int i = 0; i < 6; ++i) acc[i] += w * bf2f(lp[(pg * 6 + i) * EE + e]);
  }
#pragma unroll
  for (int i = 0; i < 6; ++i)
    rel16[(long)(p0 + pg * 6 + i) * EE + col] = f2bf(acc[i]);
}

// =====================================================================
// 256x256 8-phase bf16 MFMA GEMM (learn_hip m201 template, plain HIP)
// C[M,N] = A[M,K] * Bt[N,K]^T.  BK=64, 512 threads = 8 waves (2M x 4N),
// per-wave 128x64 output (acc[8][4]), 128 KiB double-buffered LDS.
// LDS swizzle: granule g stored at g ^ (row&7) via permuted GLOBAL source
// (rule #21) + same XOR on ds_read.  Staging schedule (deep prefetch):
//   P1: A-lo(t+1)->next      P2: A-hi(t+1)->next
//   P4: B(t+2)->cur.B (cur.B free after P3) ; vmcnt(4)
// so min issue->wait distance = 2 phases; B(t+2) stays in flight across
// the tile boundary (never vmcnt(0) in the loop).
// Epilogue: LDS transpose (reuse 128KiB after drain) -> coalesced
// 16B/lane full-line stores (kills the 1.9x write amplification).
// =====================================================================

// stage one 128x64-bf16 half-tile: 8 waves x 2 global_load_lds
__device__ __forceinline__ void stage_half(const unsigned short* g0, long Kl,
                                           unsigned short* lhalf,
                                           int w, int rlo, int qz) {
  const unsigned short* s0 = g0 + (long)(w * 16 + rlo) * Kl + qz * 8;
  async16(s0,          lhalf + w * 1024);        // rows w*16 .. +7
  async16(s0 + 8 * Kl, lhalf + w * 1024 + 512);  // rows w*16+8 .. +15
}

__device__ __forceinline__ void tile4(
    unsigned short* AP, unsigned short* BP,        // current buffer (tile t)
    unsigned short* AQ, unsigned short* BQ,        // next buffer (tile t+1)
    const unsigned short* gAt, const unsigned short* gBt, long Kl,
    int t1, int t2, int w, int rlo, int qz,
    int aBase, int bBase, int sw0, int sw1, f32x4 (&acc)[8][4]) {
  s16x8 af[4], bf[4];

  // ---- P1: a(m0-3,ks0) + b(ks0); stage A-lo(t1) -> AQ ----
#pragma unroll
  for (int i = 0; i < 4; ++i) af[i] = *(const s16x8*)&AP[(aBase + 16 * i) * 64 + sw0];
#pragma unroll
  for (int j = 0; j < 4; ++j) bf[j] = *(const s16x8*)&BP[(bBase + 16 * j) * 64 + sw0];
  stage_half(gAt + (long)t1 * 64, Kl, AQ, w, rlo, qz);
  __builtin_amdgcn_s_barrier();
  __builtin_amdgcn_s_setprio(1);
#pragma unroll
  for (int i = 0; i < 4; ++i)
#pragma unroll
    for (int j = 0; j < 4; ++j)
      acc[i][j] = __builtin_amdgcn_mfma_f32_16x16x32_bf16(af[i], bf[j], acc[i][j], 0, 0, 0);
  __builtin_amdgcn_s_setprio(0);
  __builtin_amdgcn_s_barrier();

  // ---- P2: a(m4-7,ks0); stage A-hi(t1) -> AQ+8192 ----
#pragma unroll
  for (int i = 0; i < 4; ++i) af[i] = *(const s16x8*)&AP[(aBase + 64 + 16 * i) * 64 + sw0];
  stage_half(gAt + 128 * Kl + (long)t1 * 64, Kl, AQ + 8192, w, rlo, qz);
  __builtin_amdgcn_s_barrier();
  __builtin_amdgcn_s_setprio(1);
#pragma unroll
  for (int i = 0; i < 4; ++i)
#pragma unroll
    for (int j = 0; j < 4; ++j)
      acc[4 + i][j] = __builtin_amdgcn_mfma_f32_16x16x32_bf16(af[i], bf[j], acc[4 + i][j], 0, 0, 0);
  __builtin_amdgcn_s_setprio(0);
  __builtin_amdgcn_s_barrier();

  // ---- P3: a(m0-3,ks1) + b(ks1); no stage (cur.B still being read) ----
#pragma unroll
  for (int i = 0; i < 4; ++i) af[i] = *(const s16x8*)&AP[(aBase + 16 * i) * 64 + sw1];
#pragma unroll
  for (int j = 0; j < 4; ++j) bf[j] = *(const s16x8*)&BP[(bBase + 16 * j) * 64 + sw1];
  __builtin_amdgcn_s_barrier();
  __builtin_amdgcn_s_setprio(1);
#pragma unroll
  for (int i = 0; i < 4; ++i)
#pragma unroll
    for (int j = 0; j < 4; ++j)
      acc[i][j] = __builtin_amdgcn_mfma_f32_16x16x32_bf16(af[i], bf[j], acc[i][j], 0, 0, 0);
  __builtin_amdgcn_s_setprio(0);
  __builtin_amdgcn_s_barrier();

  // ---- P4: a(m4-7,ks1); stage B(t2) -> BP (freed after P3); counted vmcnt ----
#pragma unroll
  for (int i = 0; i < 4; ++i) af[i] = *(const s16x8*)&AP[(aBase + 64 + 16 * i) * 64 + sw1];
  stage_half(gBt + (long)t2 * 64, Kl, BP, w, rlo, qz);
  stage_half(gBt + 128 * Kl + (long)t2 * 64, Kl, BP + 8192, w, rlo, qz);
  // queue: B(t1) [P4 prev, 4] , A(t1) [P1/P2, 4] , B(t2) [now, 4]
  // vmcnt(4): retire B(t1)+A(t1) (>=2 phases old), keep B(t2) in flight.
  asm volatile("s_waitcnt vmcnt(4)" ::: "memory");
  __builtin_amdgcn_s_barrier();
  __builtin_amdgcn_s_setprio(1);
#pragma unroll
  for (int i = 0; i < 4; ++i)
#pragma unroll
    for (int j = 0; j < 4; ++j)
      acc[4 + i][j] = __builtin_amdgcn_mfma_f32_16x16x32_bf16(af[i], bf[j], acc[4 + i][j], 0, 0, 0);
  __builtin_amdgcn_s_setprio(0);
  __builtin_amdgcn_s_barrier();
}

__global__ __launch_bounds__(512, 2) void k_gemm256(
    const unsigned short* __restrict__ A, const unsigned short* __restrict__ Bt,
    void* __restrict__ Cv, int M, int N, int K, int gN,
    int mode, const float* __restrict__ qscale, int c_f32) {
  __shared__ unsigned short sm[65536];   // 128 KiB: A0|B0|A1|B1, 16384 shorts each

  const int tid = threadIdx.x;
  const int w = tid >> 6;
  const int lane = tid & 63;
  const int quad = lane >> 4;
  const int l16 = lane & 15;
  const int sw = l16 & 7;
  const int rlo = lane >> 3;             // staging: row-within-8 for this lane
  const int qz = (lane & 7) ^ rlo;       // staging: inverse-swizzled source granule

  // XCD-aware chunk (bijective, nwg % 8 == 0) + GM=4 grouped m-bands inside
  // each chunk: ~32 concurrent blocks/XCD span 4 A-panels x 8 B-panels
  // instead of 1 x 18 -> ~3x less L2-miss traffic on B.
  const int nwg = gridDim.x;
  const int orig = blockIdx.x;
  const int qd = nwg >> 3;               // blocks per XCD chunk (multiple of gN)
  const int xcd = orig & 7;
  const int u = orig >> 3;               // position within chunk
  const int bandsz = 4 * gN;
  const int band = u / bandsz;
  const int rem = u - band * bandsz;
  const int mi = band * 4 + (rem & 3);
  const int ni = rem >> 2;
  const int mloc = qd / gN;              // m-tiles per chunk
  const int mt = xcd * mloc + mi;
  const int nt = ni;
  const long bm = (long)mt * 256, bn = (long)nt * 256;
  const long Kl = K;
  const unsigned short* gAt = A + bm * Kl;
  const unsigned short* gBt = Bt + bn * Kl;

  unsigned short* A0 = sm;
  unsigned short* B0 = sm + 16384;
  unsigned short* A1 = sm + 32768;
  unsigned short* B1 = sm + 49152;

  const int aBase = (w >> 2) * 128 + l16;            // wave M-panel row base
  const int bBase = (w & 3) * 64 + l16;              // wave N-panel row base
  const int sw0 = ((quad ^ sw) & 7) * 8;             // ks=0 swizzled granule offset (shorts)
  const int sw1 = (((4 | quad) ^ sw) & 7) * 8;       // ks=1

  f32x4 acc[8][4] = {};
  const int NT = K >> 6;                             // K-tiles of 64 (even)

  // ---- prologue: tile0 -> buf0; B(1) -> buf1.B; keep B(1) in flight ----
  stage_half(gAt,            Kl, A0,        w, rlo, qz);
  stage_half(gAt + 128 * Kl, Kl, A0 + 8192, w, rlo, qz);
  stage_half(gBt,            Kl, B0,        w, rlo, qz);
  stage_half(gBt + 128 * Kl, Kl, B0 + 8192, w, rlo, qz);
  stage_half(gBt + 64,            Kl, B1,        w, rlo, qz);
  stage_half(gBt + 128 * Kl + 64, Kl, B1 + 8192, w, rlo, qz);
  asm volatile("s_waitcnt vmcnt(4)" ::: "memory");   // tile0's 8 loads retired
  __builtin_amdgcn_s_barrier();

  for (int t = 0; t < NT; t += 2) {
    const int t1 = t + 1;
    const int t2 = (t + 2 == NT) ? 0 : t + 2;                 // wrap: dead re-stage, no OOB
    const int t3 = (t + 3 >= NT) ? t + 3 - NT : t + 3;
    tile4(A0, B0, A1, B1, gAt, gBt, Kl, t1, t2, w, rlo, qz, aBase, bBase, sw0, sw1, acc);
    tile4(A1, B1, A0, B0, gAt, gBt, Kl, t2, t3, w, rlo, qz, aBase, bBase, sw0, sw1, acc);
  }

  // ---- epilogue: drain in-flight staging, then LDS transpose for
  //      coalesced full-line stores.  MFMA C/D: col=lane&15, row=quad*4+reg.
  __syncthreads();   // vmcnt(0)+lgkmcnt(0)+barrier: safe to reuse sm

  const int wmq = (w >> 2) * 128;
  const int wnq = (w & 3) * 64;

  if (!c_f32) {
    // bf16 C-tile 256x256 = 128KiB exactly. 16B-granule XOR swizzle
    // g' = g ^ ((row>>2)&7) -> conflict-free writes (quads spread) & reads.
#pragma unroll
    for (int j = 0; j < 4; ++j) {
      const long col = bn + wnq + 16 * j + l16;
      float scale = 1.0f;
      if (mode == 3)
        scale = (col < 1536) ? qscale[col & (DD - 1)] : (col < 3072 ? K_SCALE_F : 1.0f);
      const int lc = wnq + 16 * j + l16;
#pragma unroll
      for (int i = 0; i < 8; ++i) {
        const int lr0 = wmq + 16 * i + quad * 4;
#pragma unroll
        for (int r = 0; r < 4; ++r) {
          const int lr = lr0 + r;
          const int gsw = (lc >> 3) ^ ((lr >> 2) & 7);
          sm[lr * 256 + gsw * 8 + (lc & 7)] = f2bf(acc[i][j][r] * scale);
        }
      }
    }
    __syncthreads();
#pragma unroll
    for (int k = 0; k < 16; ++k) {
      const int G = k * 512 + tid;            // 16B granule id, lanes consecutive
      const int row = G >> 5, gc = G & 31;
      const int gsw = gc ^ ((row >> 2) & 7);
      s16x8 vdat = *(const s16x8*)&sm[row * 256 + gsw * 8];
      *(s16x8*)&((unsigned short*)Cv)[(bm + row) * (long)N + bn + gc * 8] = vdat;
    }
  } else {
    // fp32 C-tile in two 128-row passes (128x256 f32 = 128KiB each).
    float* Cf = (float*)sm;
#pragma unroll
    for (int h = 0; h < 2; ++h) {
      if ((wmq == 0) == (h == 0)) {   // waves owning this half write their acc
#pragma unroll
        for (int j = 0; j < 4; ++j) {
          const long col = bn + wnq + 16 * j + l16;
          float scale = 1.0f;
          if (mode == 3)
            scale = (col < 1536) ? qscale[col & (DD - 1)] : (col < 3072 ? K_SCALE_F : 1.0f);
          const int lc = wnq + 16 * j + l16;
#pragma unroll
          for (int i = 0; i < 8; ++i) {
            const int lr0 = 16 * i + quad * 4;
#pragma unroll
            for (int r = 0; r < 4; ++r) {
              const int lr = lr0 + r;
              const int gsw = (lc >> 2) ^ ((lr >> 2) & 7);
              Cf[lr * 256 + gsw * 4 + (lc & 3)] = acc[i][j][r] * scale;
            }
          }
        }
      }
      __syncthreads();
#pragma unroll
      for (int k = 0; k < 16; ++k) {
        const int G = k * 512 + tid;          // 16B granule (4 floats)
        const int row = G >> 6, gc = G & 63;
        const int gsw = gc ^ ((row >> 2) & 7);
        float4 vdat = *(const float4*)&Cf[row * 256 + gsw * 4];
        *(float4*)&((float*)Cv)[(bm + h * 128 + row) * (long)N + bn + gc * 4] = vdat;
      }
      __syncthreads();
    }
  }
}

// ---- chunked local attention, one block per (b, n, h) ----
// LDS pitch 65 words -> conflict-free score/output phases.
__global__ __launch_bounds__(256) void k_attn(
    const unsigned short* __restrict__ qkv, const unsigned short* __restrict__ rel,
    unsigned short* __restrict__ attn_out, float* __restrict__ aw_out) {
  const int n = blockIdx.x;
  const int b = blockIdx.y;
  const int h = blockIdx.z;
  const int t = threadIdx.x;

  __shared__ unsigned int lq[CHK * PITCH];
  __shared__ unsigned int lk[CTXW * PITCH];
  __shared__ unsigned int lv[CTXW * PITCH];
  __shared__ unsigned int lr[CTXW * PITCH];
  __shared__ float sac[CHK * CTXW];
  __shared__ float sbd[CHK * CTXW];
  __shared__ float smax[CHK];
  __shared__ float sinv[CHK];

  const long tok0 = (long)b * SEQ + (long)n * CHK;
  const long hq = (long)h * DD;

  // ---- stage q: 12 rows x 16 uint4 ----
  for (int u = t; u < CHK * 16; u += 256) {
    int r = u >> 4, w4 = u & 15;
    uint4 x = *(const uint4*)&qkv[(tok0 + r) * QKVP + hq + w4 * 8];
    unsigned int* d = &lq[r * PITCH + w4 * 4];
    d[0] = x.x; d[1] = x.y; d[2] = x.z; d[3] = x.w;
  }
  // ---- stage k, v (with left halo), rel: 24 rows x 16 uint4 each ----
  for (int u = t; u < CTXW * 16; u += 256) {
    int r = u >> 4, w4 = u & 15;
    int s = n * CHK + r - 12;
    uint4 kx, vx;
    if (s >= 0) {
      const unsigned short* base = &qkv[((long)b * SEQ + s) * QKVP + hq];
      kx = *(const uint4*)&base[1536 + w4 * 8];
      vx = *(const uint4*)&base[3072 + w4 * 8];
    } else {
      kx = make_uint4(0, 0, 0, 0);
      vx = make_uint4(0, 0, 0, 0);
    }
    uint4 rx = *(const uint4*)&rel[(long)r * EE + hq + w4 * 8];
    unsigned int* dk = &lk[r * PITCH + w4 * 4];
    unsigned int* dv = &lv[r * PITCH + w4 * 4];
    unsigned int* dr = &lr[r * PITCH + w4 * 4];
    dk[0] = kx.x; dk[1] = kx.y; dk[2] = kx.z; dk[3] = kx.w;
    dv[0] = vx.x; dv[1] = vx.y; dv[2] = vx.z; dv[3] = vx.w;
    dr[0] = rx.x; dr[1] = rx.y; dr[2] = rx.z; dr[3] = rx.w;
  }
  __syncthreads();

  // ---- scores: 288 (c,j) pairs, dot over 64 dwords (conflict-free banks) ----
  for (int p = t; p < CHK * CTXW; p += 256) {
    int c = p / CTXW, j = p - c * CTXW;
    const unsigned int* uq = &lq[c * PITCH];
    const unsigned int* uk = &lk[j * PITCH];
    const unsigned int* ur = &lr[j * PITCH];
    float ac = 0.f, bd = 0.f;
#pragma unroll 16
    for (int d2 = 0; d2 < DD / 2; ++d2) {
      float a0, a1, k0f, k1f, r0, r1;
      bf2f2(uq[d2], a0, a1);
      bf2f2(uk[d2], k0f, k1f);
      bf2f2(ur[d2], r0, r1);
      ac += a0 * k0f + a1 * k1f;
      bd += a0 * r0 + a1 * r1;
    }
    sac[p] = ac;
    sbd[p] = bd;
  }
  __syncthreads();

  // ---- rel-shift + softcap (parallel over 288) ----
  for (int p = t; p < CHK * CTXW; p += 256) {
    int c = p / CTXW, j = p - c * CTXW;
    float y;
    if (j >= c) y = sbd[c * CTXW + (j - c)];
    else if (j == c - 1) y = 0.f;
    else y = sbd[(c - 1) * CTXW + (j - c + CTXW + 1)];
    float x = (sac[p] + y) * 0.02f;
    x = fminf(fmaxf(x, -15.f), 15.f);
    float e2 = __expf(2.f * x);
    sac[p] = 50.f * (e2 - 1.f) / (e2 + 1.f);   // 50*tanh(x)
  }
  __syncthreads();

  // ---- row max ----
  if (t < CHK) {
    float m = -3.0e38f;
#pragma unroll
    for (int j = 0; j < CTXW; ++j) m = fmaxf(m, sac[t * CTXW + j]);
    smax[t] = m;
  }
  __syncthreads();

  // ---- exp (parallel) ----
  for (int p = t; p < CHK * CTXW; p += 256) {
    int c = p / CTXW;
    sbd[p] = __expf(sac[p] - smax[c]);
  }
  __syncthreads();

  // ---- row sum ----
  if (t < CHK) {
    float s = 0.f;
#pragma unroll
    for (int j = 0; j < CTXW; ++j) s += sbd[t * CTXW + j];
    sinv[t] = 1.f / s;
  }
  __syncthreads();

  // ---- normalize + write attn_weights ----
  for (int p = t; p < CHK * CTXW; p += 256) {
    int c = p / CTXW, j = p - c * CTXW;
    float w = sbd[p] * sinv[c];
    sac[p] = w;
    aw_out[((((long)b * HH + h) * NBLK + n) * CHK + c) * CTXW + j] = w;
  }
  __syncthreads();

  // ---- output: O[c][d] = sum_j w[c][j] * v[j][d], dword-paired d ----
  for (int p = t; p < CHK * (DD / 2); p += 256) {
    int c = p >> 6, d2 = p & 63;
    float a0 = 0.f, a1 = 0.f;
#pragma unroll
    for (int j = 0; j < CTXW; ++j) {
      float w = sac[c * CTXW + j];
      float v0, v1;
      bf2f2(lv[j * PITCH + d2], v0, v1);
      a0 += w * v0; a1 += w * v1;
    }
    unsigned int packed = ((unsigned int)f2bf(a1) << 16) | (unsigned int)f2bf(a0);
    *(unsigned int*)&attn_out[(tok0 + c) * EE + hq + d2 * 2] = packed;
  }
}

extern "C" void kernel_launch(void* const* d_in, const int* in_sizes, int n_in,
                              void* d_out, int out_size, void* d_ws, size_t ws_size,
                              hipStream_t stream) {
  const float* hs     = (const float*)d_in[0];
  const float* pos    = (const float*)d_in[1];
  const float* w_q    = (const float*)d_in[2];
  const float* w_k    = (const float*)d_in[3];
  const float* w_v    = (const float*)d_in[4];
  const float* w_post = (const float*)d_in[5];
  const float* w_rel  = (const float*)d_in[6];
  const float* pds    = (const float*)d_in[7];

  char* ws = (char*)d_ws;
  const size_t TOKB = (size_t)MTOK * EE * 2;        // bytes per [MTOK,EE] bf16
  const size_t WB   = (size_t)EE * EE * 2;
  unsigned short* hs16   = (unsigned short*)(ws);
  unsigned short* qkv16  = (unsigned short*)(ws + TOKB);           // [MTOK][4608]
  unsigned short* wq16   = (unsigned short*)(ws + 4 * TOKB);       // wq|wk|wv contiguous
  unsigned short* wk16   = (unsigned short*)(ws + 4 * TOKB + WB);
  unsigned short* wv16   = (unsigned short*)(ws + 4 * TOKB + 2 * WB);
  unsigned short* wp16   = (unsigned short*)(ws + 4 * TOKB + 3 * WB);
  unsigned short* rel16  = (unsigned short*)(ws + 4 * TOKB + 4 * WB);
  float* qscale          = (float*)(ws + 4 * TOKB + 4 * WB + CTXW * EE * 2);
  unsigned short* attn16 = hs16;  // hs16 dead after qkv GEMM

  float* out = (float*)d_out;
  float* aw  = out + (size_t)MTOK * EE;

  // bf16 conversions
  k_cvt<<<36864, 256, 0, stream>>>((const float4*)hs, (ushort4*)hs16, MTOK * EE / 4);
  k_cvt<<<2304, 256, 0, stream>>>((const float4*)w_q, (ushort4*)wq16, EE * EE / 4);
  k_cvt<<<2304, 256, 0, stream>>>((const float4*)w_k, (ushort4*)wk16, EE * EE / 4);
  k_cvt<<<2304, 256, 0, stream>>>((const float4*)w_v, (ushort4*)wv16, EE * EE / 4);
  k_cvt<<<2304, 256, 0, stream>>>((const float4*)w_post, (ushort4*)wp16, EE * EE / 4);
  k_qscale<<<1, 128, 0, stream>>>(pds, qscale);
  k_rel<<<dim3(12, 2), 256, 0, stream>>>(pos, w_rel, rel16);

  // fused q|k|v projection: Bt = [wq;wk;wv] (contiguous), N=4608, scales in epilogue
  k_gemm256<<<dim3((MTOK / 256) * (QKVP / 256)), 512, 0, stream>>>(
      hs16, wq16, qkv16, MTOK, QKVP, EE, QKVP / 256, 3, qscale, 0);

  // attention: one block per (b, n, h)
  k_attn<<<dim3(NBLK, NBATCH, HH), 256, 0, stream>>>(qkv16, rel16, attn16, aw);

  // output projection -> fp32 d_out
  k_gemm256<<<dim3((MTOK / 256) * (EE / 256)), 512, 0, stream>>>(
      attn16, wp16, out, MTOK, EE, EE, EE / 256, 0, nullptr, 1);
}

// Round 3
// 987.336 us; speedup vs baseline: 1.2777x; 1.0464x over previous
//
#include <hip/hip_runtime.h>
#include <hip/hip_bf16.h>

// ---- problem constants ----
#define HH 12
#define DD 128
#define EE 1536
#define QKVP 4608       // fused q|k|v row pitch (shorts)
#define NBATCH 8
#define SEQ 3072
#define NBLK 256        // SEQ / CHK
#define CHK 12
#define CTXW 24
#define MTOK 24576      // NBATCH * SEQ

#define Q_SCALE_BASE 0.12751743f   // D^-0.5 / ln2
#define K_SCALE_F 1.8946361322f    // ln(1+e) / ln2

typedef short s16x8 __attribute__((ext_vector_type(8)));
typedef float f32x4 __attribute__((ext_vector_type(4)));

__device__ __forceinline__ float bf2f(unsigned short u) {
  return __builtin_bit_cast(float, ((unsigned int)u) << 16);
}
__device__ __forceinline__ unsigned short f2bf(float f) {
  unsigned int u = __builtin_bit_cast(unsigned int, f);
  u += 0x7fffu + ((u >> 16) & 1u);   // round-to-nearest-even
  return (unsigned short)(u >> 16);
}
__device__ __forceinline__ void bf2f2(unsigned int u, float& lo, float& hi) {
  lo = __builtin_bit_cast(float, u << 16);
  hi = __builtin_bit_cast(float, u & 0xffff0000u);
}

// async global->LDS, 16B per lane; lds dest must be wave-uniform base (lands at base + lane*16)
__device__ __forceinline__ void async16(const void* g, void* l) {
  __builtin_amdgcn_global_load_lds(
      (const __attribute__((address_space(1))) unsigned int*)g,
      (__attribute__((address_space(3))) unsigned int*)l, 16, 0, 0);
}

// ---- fp32 -> bf16 convert (vectorized) ----
__global__ __launch_bounds__(256) void k_cvt(const float4* __restrict__ in,
                                             ushort4* __restrict__ out, int n4) {
  int i = blockIdx.x * 256 + threadIdx.x;
  if (i < n4) {
    float4 v = in[i];
    ushort4 o;
    o.x = f2bf(v.x); o.y = f2bf(v.y); o.z = f2bf(v.z); o.w = f2bf(v.w);
    out[i] = o;
  }
}

// ---- per-dim query scale: Q_SCALE * softplus(per_dim_scale) ----
__global__ void k_qscale(const float* __restrict__ pds, float* __restrict__ qs) {
  int d = threadIdx.x;
  if (d < DD) {
    float x = pds[d];
    float sp = (x > 20.f) ? x : log1pf(expf(x));
    qs[d] = Q_SCALE_BASE * sp;
  }
}

// ---- rel_k = pos_emb @ w_rel.T  -> bf16 [CTXW][EE] ----
__global__ __launch_bounds__(256) void k_rel(const float* __restrict__ pos,
                                             const float* __restrict__ w_rel,
                                             unsigned short* __restrict__ rel16) {
  __shared__ unsigned short lp[12 * EE];
  const int t = threadIdx.x;
  const int p0 = blockIdx.y * 12;
  for (int i = t; i < 12 * EE / 4; i += 256) {
    float4 x = ((const float4*)(pos + (long)p0 * EE))[i];
    ushort4 o; o.x = f2bf(x.x); o.y = f2bf(x.y); o.z = f2bf(x.z); o.w = f2bf(x.w);
    ((ushort4*)lp)[i] = o;
  }
  __syncthreads();
  const int col = blockIdx.x * 128 + (t & 127);
  const int pg = t >> 7;  // 0 or 1 -> 6 p-rows each
  float acc[6] = {0.f, 0.f, 0.f, 0.f, 0.f, 0.f};
  const float* wr = w_rel + (long)col * EE;
  for (int e = 0; e < EE; e += 4) {
    float4 w4 = *(const float4*)&wr[e];
#pragma unroll
    for (int i = 0; i < 6; ++i) {
      const unsigned short* lpr = &lp[(pg * 6 + i) * EE + e];
      unsigned int u01 = *(const unsigned int*)lpr;
      unsigned int u23 = *(const unsigned int*)(lpr + 2);
      float a0, a1, a2, a3;
      bf2f2(u01, a0, a1); bf2f2(u23, a2, a3);
      acc[i] += w4.x * a0 + w4.y * a1 + w4.z * a2 + w4.w * a3;
    }
  }
#pragma unroll
  for (int i = 0; i < 6; ++i)
    rel16[(long)(p0 + pg * 6 + i) * EE + col] = f2bf(acc[i]);
}

// =====================================================================
// 256x256 8-phase bf16 MFMA GEMM (learn_hip m201 template, plain HIP)
// (unchanged from R2 — see R2 notes; MfmaUtil 44.5%, conflicts ~0)
// =====================================================================

__device__ __forceinline__ void stage_half(const unsigned short* g0, long Kl,
                                           unsigned short* lhalf,
                                           int w, int rlo, int qz) {
  const unsigned short* s0 = g0 + (long)(w * 16 + rlo) * Kl + qz * 8;
  async16(s0,          lhalf + w * 1024);        // rows w*16 .. +7
  async16(s0 + 8 * Kl, lhalf + w * 1024 + 512);  // rows w*16+8 .. +15
}

__device__ __forceinline__ void tile4(
    unsigned short* AP, unsigned short* BP,        // current buffer (tile t)
    unsigned short* AQ, unsigned short* BQ,        // next buffer (tile t+1)
    const unsigned short* gAt, const unsigned short* gBt, long Kl,
    int t1, int t2, int w, int rlo, int qz,
    int aBase, int bBase, int sw0, int sw1, f32x4 (&acc)[8][4]) {
  s16x8 af[4], bf[4];

  // ---- P1: a(m0-3,ks0) + b(ks0); stage A-lo(t1) -> AQ ----
#pragma unroll
  for (int i = 0; i < 4; ++i) af[i] = *(const s16x8*)&AP[(aBase + 16 * i) * 64 + sw0];
#pragma unroll
  for (int j = 0; j < 4; ++j) bf[j] = *(const s16x8*)&BP[(bBase + 16 * j) * 64 + sw0];
  stage_half(gAt + (long)t1 * 64, Kl, AQ, w, rlo, qz);
  __builtin_amdgcn_s_barrier();
  __builtin_amdgcn_s_setprio(1);
#pragma unroll
  for (int i = 0; i < 4; ++i)
#pragma unroll
    for (int j = 0; j < 4; ++j)
      acc[i][j] = __builtin_amdgcn_mfma_f32_16x16x32_bf16(af[i], bf[j], acc[i][j], 0, 0, 0);
  __builtin_amdgcn_s_setprio(0);
  __builtin_amdgcn_s_barrier();

  // ---- P2: a(m4-7,ks0); stage A-hi(t1) -> AQ+8192 ----
#pragma unroll
  for (int i = 0; i < 4; ++i) af[i] = *(const s16x8*)&AP[(aBase + 64 + 16 * i) * 64 + sw0];
  stage_half(gAt + 128 * Kl + (long)t1 * 64, Kl, AQ + 8192, w, rlo, qz);
  __builtin_amdgcn_s_barrier();
  __builtin_amdgcn_s_setprio(1);
#pragma unroll
  for (int i = 0; i < 4; ++i)
#pragma unroll
    for (int j = 0; j < 4; ++j)
      acc[4 + i][j] = __builtin_amdgcn_mfma_f32_16x16x32_bf16(af[i], bf[j], acc[4 + i][j], 0, 0, 0);
  __builtin_amdgcn_s_setprio(0);
  __builtin_amdgcn_s_barrier();

  // ---- P3: a(m0-3,ks1) + b(ks1); no stage (cur.B still being read) ----
#pragma unroll
  for (int i = 0; i < 4; ++i) af[i] = *(const s16x8*)&AP[(aBase + 16 * i) * 64 + sw1];
#pragma unroll
  for (int j = 0; j < 4; ++j) bf[j] = *(const s16x8*)&BP[(bBase + 16 * j) * 64 + sw1];
  __builtin_amdgcn_s_barrier();
  __builtin_amdgcn_s_setprio(1);
#pragma unroll
  for (int i = 0; i < 4; ++i)
#pragma unroll
    for (int j = 0; j < 4; ++j)
      acc[i][j] = __builtin_amdgcn_mfma_f32_16x16x32_bf16(af[i], bf[j], acc[i][j], 0, 0, 0);
  __builtin_amdgcn_s_setprio(0);
  __builtin_amdgcn_s_barrier();

  // ---- P4: a(m4-7,ks1); stage B(t2) -> BP (freed after P3); counted vmcnt ----
#pragma unroll
  for (int i = 0; i < 4; ++i) af[i] = *(const s16x8*)&AP[(aBase + 64 + 16 * i) * 64 + sw1];
  stage_half(gBt + (long)t2 * 64, Kl, BP, w, rlo, qz);
  stage_half(gBt + 128 * Kl + (long)t2 * 64, Kl, BP + 8192, w, rlo, qz);
  // queue: B(t1) [P4 prev, 4] , A(t1) [P1/P2, 4] , B(t2) [now, 4]
  // vmcnt(4): retire B(t1)+A(t1) (>=2 phases old), keep B(t2) in flight.
  asm volatile("s_waitcnt vmcnt(4)" ::: "memory");
  __builtin_amdgcn_s_barrier();
  __builtin_amdgcn_s_setprio(1);
#pragma unroll
  for (int i = 0; i < 4; ++i)
#pragma unroll
    for (int j = 0; j < 4; ++j)
      acc[4 + i][j] = __builtin_amdgcn_mfma_f32_16x16x32_bf16(af[i], bf[j], acc[4 + i][j], 0, 0, 0);
  __builtin_amdgcn_s_setprio(0);
  __builtin_amdgcn_s_barrier();
}

__global__ __launch_bounds__(512, 2) void k_gemm256(
    const unsigned short* __restrict__ A, const unsigned short* __restrict__ Bt,
    void* __restrict__ Cv, int M, int N, int K, int gN,
    int mode, const float* __restrict__ qscale, int c_f32) {
  __shared__ unsigned short sm[65536];   // 128 KiB: A0|B0|A1|B1, 16384 shorts each

  const int tid = threadIdx.x;
  const int w = tid >> 6;
  const int lane = tid & 63;
  const int quad = lane >> 4;
  const int l16 = lane & 15;
  const int sw = l16 & 7;
  const int rlo = lane >> 3;             // staging: row-within-8 for this lane
  const int qz = (lane & 7) ^ rlo;       // staging: inverse-swizzled source granule

  // XCD-aware chunk (bijective, nwg % 8 == 0) + GM=4 grouped m-bands.
  const int nwg = gridDim.x;
  const int orig = blockIdx.x;
  const int qd = nwg >> 3;               // blocks per XCD chunk (multiple of gN)
  const int xcd = orig & 7;
  const int u = orig >> 3;               // position within chunk
  const int bandsz = 4 * gN;
  const int band = u / bandsz;
  const int rem = u - band * bandsz;
  const int mi = band * 4 + (rem & 3);
  const int ni = rem >> 2;
  const int mloc = qd / gN;              // m-tiles per chunk
  const int mt = xcd * mloc + mi;
  const int nt = ni;
  const long bm = (long)mt * 256, bn = (long)nt * 256;
  const long Kl = K;
  const unsigned short* gAt = A + bm * Kl;
  const unsigned short* gBt = Bt + bn * Kl;

  unsigned short* A0 = sm;
  unsigned short* B0 = sm + 16384;
  unsigned short* A1 = sm + 32768;
  unsigned short* B1 = sm + 49152;

  const int aBase = (w >> 2) * 128 + l16;            // wave M-panel row base
  const int bBase = (w & 3) * 64 + l16;              // wave N-panel row base
  const int sw0 = ((quad ^ sw) & 7) * 8;             // ks=0 swizzled granule offset (shorts)
  const int sw1 = (((4 | quad) ^ sw) & 7) * 8;       // ks=1

  f32x4 acc[8][4] = {};
  const int NT = K >> 6;                             // K-tiles of 64 (even)

  // ---- prologue: tile0 -> buf0; B(1) -> buf1.B; keep B(1) in flight ----
  stage_half(gAt,            Kl, A0,        w, rlo, qz);
  stage_half(gAt + 128 * Kl, Kl, A0 + 8192, w, rlo, qz);
  stage_half(gBt,            Kl, B0,        w, rlo, qz);
  stage_half(gBt + 128 * Kl, Kl, B0 + 8192, w, rlo, qz);
  stage_half(gBt + 64,            Kl, B1,        w, rlo, qz);
  stage_half(gBt + 128 * Kl + 64, Kl, B1 + 8192, w, rlo, qz);
  asm volatile("s_waitcnt vmcnt(4)" ::: "memory");   // tile0's 8 loads retired
  __builtin_amdgcn_s_barrier();

  for (int t = 0; t < NT; t += 2) {
    const int t1 = t + 1;
    const int t2 = (t + 2 == NT) ? 0 : t + 2;                 // wrap: dead re-stage, no OOB
    const int t3 = (t + 3 >= NT) ? t + 3 - NT : t + 3;
    tile4(A0, B0, A1, B1, gAt, gBt, Kl, t1, t2, w, rlo, qz, aBase, bBase, sw0, sw1, acc);
    tile4(A1, B1, A0, B0, gAt, gBt, Kl, t2, t3, w, rlo, qz, aBase, bBase, sw0, sw1, acc);
  }

  // ---- epilogue: drain, then LDS transpose for coalesced full-line stores.
  __syncthreads();

  const int wmq = (w >> 2) * 128;
  const int wnq = (w & 3) * 64;

  if (!c_f32) {
#pragma unroll
    for (int j = 0; j < 4; ++j) {
      const long col = bn + wnq + 16 * j + l16;
      float scale = 1.0f;
      if (mode == 3)
        scale = (col < 1536) ? qscale[col & (DD - 1)] : (col < 3072 ? K_SCALE_F : 1.0f);
      const int lc = wnq + 16 * j + l16;
#pragma unroll
      for (int i = 0; i < 8; ++i) {
        const int lr0 = wmq + 16 * i + quad * 4;
#pragma unroll
        for (int r = 0; r < 4; ++r) {
          const int lr = lr0 + r;
          const int gsw = (lc >> 3) ^ ((lr >> 2) & 7);
          sm[lr * 256 + gsw * 8 + (lc & 7)] = f2bf(acc[i][j][r] * scale);
        }
      }
    }
    __syncthreads();
#pragma unroll
    for (int k = 0; k < 16; ++k) {
      const int G = k * 512 + tid;            // 16B granule id, lanes consecutive
      const int row = G >> 5, gc = G & 31;
      const int gsw = gc ^ ((row >> 2) & 7);
      s16x8 vdat = *(const s16x8*)&sm[row * 256 + gsw * 8];
      *(s16x8*)&((unsigned short*)Cv)[(bm + row) * (long)N + bn + gc * 8] = vdat;
    }
  } else {
    float* Cf = (float*)sm;
#pragma unroll
    for (int h = 0; h < 2; ++h) {
      if ((wmq == 0) == (h == 0)) {   // waves owning this half write their acc
#pragma unroll
        for (int j = 0; j < 4; ++j) {
          const long col = bn + wnq + 16 * j + l16;
          float scale = 1.0f;
          if (mode == 3)
            scale = (col < 1536) ? qscale[col & (DD - 1)] : (col < 3072 ? K_SCALE_F : 1.0f);
          const int lc = wnq + 16 * j + l16;
#pragma unroll
          for (int i = 0; i < 8; ++i) {
            const int lr0 = 16 * i + quad * 4;
#pragma unroll
            for (int r = 0; r < 4; ++r) {
              const int lr = lr0 + r;
              const int gsw = (lc >> 2) ^ ((lr >> 2) & 7);
              Cf[lr * 256 + gsw * 4 + (lc & 3)] = acc[i][j][r] * scale;
            }
          }
        }
      }
      __syncthreads();
#pragma unroll
      for (int k = 0; k < 16; ++k) {
        const int G = k * 512 + tid;          // 16B granule (4 floats)
        const int row = G >> 6, gc = G & 63;
        const int gsw = gc ^ ((row >> 2) & 7);
        float4 vdat = *(const float4*)&Cf[row * 256 + gsw * 4];
        *(float4*)&((float*)Cv)[(bm + h * 128 + row) * (long)N + bn + gc * 4] = vdat;
      }
      __syncthreads();
    }
  }
}

// =====================================================================
// chunked local attention via MFMA, one block (4 waves) per (b, n, h).
// S = Q K^T and BD = Q rel^T are 16x16x32 bf16 MFMAs (A = Q rows,
// B = K/rel rows — same operand convention as k_gemm256).  PV uses
// V^T staged transposed in LDS (pitch 40 = 8-bank spread).  j padded
// 24->32 with ZEROED W cols and V^T cols (0*0, no NaN from pads);
// garbage S rows>=12 / cols>=24 are column/row-independent & discarded.
// =====================================================================
__global__ __launch_bounds__(256) void k_attn(
    const unsigned short* __restrict__ qkv, const unsigned short* __restrict__ rel,
    unsigned short* __restrict__ attn_out, float* __restrict__ aw_out) {
  const int n = blockIdx.x;
  const int b = blockIdx.y;
  const int h = blockIdx.z;
  const int t = threadIdx.x;
  const int wv = t >> 6;
  const int lane = t & 63;
  const int quad = lane >> 4;
  const int l16 = lane & 15;

  __shared__ unsigned short lq[16 * 128];    // Q rows (12 used), granule-swizzled
  __shared__ unsigned short lk[32 * 128];    // K rows (24 used), granule-swizzled
  __shared__ unsigned short lrel[32 * 128];  // rel rows (24 used)
  __shared__ unsigned short lvt[128 * 40];   // V^T [d][j], cols 24-31 zeroed
  __shared__ unsigned short lw[16 * 40];     // softmax weights bf16, cols 24-31 zero
  __shared__ float sac[16 * 33];
  __shared__ float sbd[16 * 33];
  __shared__ unsigned short sO[12 * 136];
  __shared__ float smax[12], sinv[12];

  const long tok0 = (long)b * SEQ + (long)n * CHK;
  const long hq = (long)h * DD;

  // ---- stage q: 12 rows x 16 granules ----
  for (int u = t; u < 192; u += 256) {
    int r = u >> 4, w4 = u & 15;
    uint4 x = *(const uint4*)&qkv[(tok0 + r) * QKVP + hq + w4 * 8];
    *(uint4*)&lq[r * 128 + ((w4 ^ (r & 7)) * 8)] = x;
  }
  // ---- stage k (halo-zeroed) + rel: 24 rows x 16 granules each ----
  for (int u = t; u < 384; u += 256) {
    int r = u >> 4, w4 = u & 15;
    int s = n * CHK + r - 12;
    uint4 kx = make_uint4(0, 0, 0, 0);
    if (s >= 0) kx = *(const uint4*)&qkv[((long)b * SEQ + s) * QKVP + hq + 1536 + w4 * 8];
    *(uint4*)&lk[r * 128 + ((w4 ^ (r & 7)) * 8)] = kx;
    uint4 rx = *(const uint4*)&rel[(long)r * EE + hq + w4 * 8];
    *(uint4*)&lrel[r * 128 + ((w4 ^ (r & 7)) * 8)] = rx;
  }
  // ---- stage v TRANSPOSED: [j][d] -> lvt[d][j], rotated writes for banks ----
  for (int u = t; u < 384; u += 256) {
    int r = u >> 4, d16 = u & 15, d0 = d16 * 8;
    int s = n * CHK + r - 12;
    uint4 vx = make_uint4(0, 0, 0, 0);
    if (s >= 0) vx = *(const uint4*)&qkv[((long)b * SEQ + s) * QKVP + hq + 3072 + d0];
    unsigned short vs[8];
    *(uint4*)vs = vx;
#pragma unroll
    for (int i = 0; i < 8; ++i) {
      int ii = (i + d16) & 7;
      lvt[(d0 + ii) * 40 + r] = vs[ii];
    }
  }
  // ---- zero pads: lvt cols 24-31 (all 128 rows), lw entirely ----
  for (int u = t; u < 128; u += 256)
    *(uint4*)&lvt[u * 40 + 24] = make_uint4(0, 0, 0, 0);
  for (int u = t; u < 80; u += 256)
    *(uint4*)&lw[u * 8] = make_uint4(0, 0, 0, 0);
  __syncthreads();

  // ---- QK^T and Q rel^T via MFMA: wave 0/1 -> ac ntile 0/1, wave 2/3 -> bd ----
  {
    const unsigned short* bsrc = (wv < 2) ? lk : lrel;
    const int nt = wv & 1;
    f32x4 acc = {};
#pragma unroll
    for (int dc = 0; dc < 4; ++dc) {
      const int g = dc * 4 + quad;
      s16x8 a = *(const s16x8*)&lq[l16 * 128 + ((g ^ (l16 & 7)) * 8)];
      const int rB = nt * 16 + l16;
      s16x8 bb = *(const s16x8*)&bsrc[rB * 128 + ((g ^ (rB & 7)) * 8)];
      acc = __builtin_amdgcn_mfma_f32_16x16x32_bf16(a, bb, acc, 0, 0, 0);
    }
    float* dstp = (wv < 2) ? sac : sbd;
#pragma unroll
    for (int r = 0; r < 4; ++r)
      dstp[(quad * 4 + r) * 33 + nt * 16 + l16] = acc[r];
  }
  __syncthreads();

  // ---- rel-shift + softcap (parallel over 288) ----
  for (int p = t; p < CHK * CTXW; p += 256) {
    int c = p / CTXW, j = p - c * CTXW;
    float y;
    if (j >= c) y = sbd[c * 33 + (j - c)];
    else if (j == c - 1) y = 0.f;
    else y = sbd[(c - 1) * 33 + (j - c + CTXW + 1)];
    float x = (sac[c * 33 + j] + y) * 0.02f;
    x = fminf(fmaxf(x, -15.f), 15.f);
    float e2 = __expf(2.f * x);
    sac[c * 33 + j] = 50.f * (e2 - 1.f) / (e2 + 1.f);   // 50*tanh(x)
  }
  __syncthreads();

  // ---- row max ----
  if (t < CHK) {
    float m = -3.0e38f;
#pragma unroll
    for (int j = 0; j < CTXW; ++j) m = fmaxf(m, sac[t * 33 + j]);
    smax[t] = m;
  }
  __syncthreads();

  // ---- exp ----
  for (int p = t; p < CHK * CTXW; p += 256) {
    int c = p / CTXW, j = p - c * CTXW;
    sbd[c * 33 + j] = __expf(sac[c * 33 + j] - smax[c]);
  }
  __syncthreads();

  // ---- row sum ----
  if (t < CHK) {
    float s = 0.f;
#pragma unroll
    for (int j = 0; j < CTXW; ++j) s += sbd[t * 33 + j];
    sinv[t] = 1.f / s;
  }
  __syncthreads();

  // ---- normalize + write attn_weights + pack W to bf16 LDS ----
  for (int p = t; p < CHK * CTXW; p += 256) {
    int c = p / CTXW, j = p - c * CTXW;
    float wgt = sbd[c * 33 + j] * sinv[c];
    aw_out[((((long)b * HH + h) * NBLK + n) * CHK + c) * CTXW + j] = wgt;
    lw[c * 40 + j] = f2bf(wgt);
  }
  __syncthreads();

  // ---- PV: wave wv handles d-tiles 2wv, 2wv+1 ----
  {
    s16x8 afw = *(const s16x8*)&lw[l16 * 40 + quad * 8];
#pragma unroll
    for (int e = 0; e < 2; ++e) {
      const int dnt = wv * 2 + e;
      s16x8 bv = *(const s16x8*)&lvt[(dnt * 16 + l16) * 40 + quad * 8];
      f32x4 o = __builtin_amdgcn_mfma_f32_16x16x32_bf16(afw, bv, (f32x4){}, 0, 0, 0);
#pragma unroll
      for (int r = 0; r < 4; ++r) {
        const int row = quad * 4 + r;
        if (row < CHK) sO[row * 136 + dnt * 16 + l16] = f2bf(o[r]);
      }
    }
  }
  __syncthreads();

  // ---- coalesced store of O ----
  for (int u = t; u < 192; u += 256) {
    int r = u >> 4, w4 = u & 15;
    uint4 x = *(const uint4*)&sO[r * 136 + w4 * 8];
    *(uint4*)&attn_out[(tok0 + r) * EE + hq + w4 * 8] = x;
  }
}

extern "C" void kernel_launch(void* const* d_in, const int* in_sizes, int n_in,
                              void* d_out, int out_size, void* d_ws, size_t ws_size,
                              hipStream_t stream) {
  const float* hs     = (const float*)d_in[0];
  const float* pos    = (const float*)d_in[1];
  const float* w_q    = (const float*)d_in[2];
  const float* w_k    = (const float*)d_in[3];
  const float* w_v    = (const float*)d_in[4];
  const float* w_post = (const float*)d_in[5];
  const float* w_rel  = (const float*)d_in[6];
  const float* pds    = (const float*)d_in[7];

  char* ws = (char*)d_ws;
  const size_t TOKB = (size_t)MTOK * EE * 2;        // bytes per [MTOK,EE] bf16
  const size_t WB   = (size_t)EE * EE * 2;
  unsigned short* hs16   = (unsigned short*)(ws);
  unsigned short* qkv16  = (unsigned short*)(ws + TOKB);           // [MTOK][4608]
  unsigned short* wq16   = (unsigned short*)(ws + 4 * TOKB);       // wq|wk|wv contiguous
  unsigned short* wk16   = (unsigned short*)(ws + 4 * TOKB + WB);
  unsigned short* wv16   = (unsigned short*)(ws + 4 * TOKB + 2 * WB);
  unsigned short* wp16   = (unsigned short*)(ws + 4 * TOKB + 3 * WB);
  unsigned short* rel16  = (unsigned short*)(ws + 4 * TOKB + 4 * WB);
  float* qscale          = (float*)(ws + 4 * TOKB + 4 * WB + CTXW * EE * 2);
  unsigned short* attn16 = hs16;  // hs16 dead after qkv GEMM

  float* out = (float*)d_out;
  float* aw  = out + (size_t)MTOK * EE;

  // bf16 conversions
  k_cvt<<<36864, 256, 0, stream>>>((const float4*)hs, (ushort4*)hs16, MTOK * EE / 4);
  k_cvt<<<2304, 256, 0, stream>>>((const float4*)w_q, (ushort4*)wq16, EE * EE / 4);
  k_cvt<<<2304, 256, 0, stream>>>((const float4*)w_k, (ushort4*)wk16, EE * EE / 4);
  k_cvt<<<2304, 256, 0, stream>>>((const float4*)w_v, (ushort4*)wv16, EE * EE / 4);
  k_cvt<<<2304, 256, 0, stream>>>((const float4*)w_post, (ushort4*)wp16, EE * EE / 4);
  k_qscale<<<1, 128, 0, stream>>>(pds, qscale);
  k_rel<<<dim3(12, 2), 256, 0, stream>>>(pos, w_rel, rel16);

  // fused q|k|v projection: Bt = [wq;wk;wv] (contiguous), N=4608, scales in epilogue
  k_gemm256<<<dim3((MTOK / 256) * (QKVP / 256)), 512, 0, stream>>>(
      hs16, wq16, qkv16, MTOK, QKVP, EE, QKVP / 256, 3, qscale, 0);

  // attention: one block per (b, n, h)
  k_attn<<<dim3(NBLK, NBATCH, HH), 256, 0, stream>>>(qkv16, rel16, attn16, aw);

  // output projection -> fp32 d_out
  k_gemm256<<<dim3((MTOK / 256) * (EE / 256)), 512, 0, stream>>>(
      attn16, wp16, out, MTOK, EE, EE, EE / 256, 0, nullptr, 1);
}

// Round 4
// 931.451 us; speedup vs baseline: 1.3544x; 1.0600x over previous
//
#include <hip/hip_runtime.h>
#include <hip/hip_bf16.h>

// ---- problem constants ----
#define HH 12
#define DD 128
#define EE 1536
#define QKVP 4608       // fused q|k|v row pitch (shorts)
#define NBATCH 8
#define SEQ 3072
#define NBLK 256        // SEQ / CHK
#define CHK 12
#define CTXW 24
#define MTOK 24576      // NBATCH * SEQ

#define Q_SCALE_BASE 0.12751743f   // D^-0.5 / ln2
#define K_SCALE_F 1.8946361322f    // ln(1+e) / ln2

typedef short s16x8 __attribute__((ext_vector_type(8)));
typedef float f32x4 __attribute__((ext_vector_type(4)));

__device__ __forceinline__ float bf2f(unsigned short u) {
  return __builtin_bit_cast(float, ((unsigned int)u) << 16);
}
__device__ __forceinline__ unsigned short f2bf(float f) {
  unsigned int u = __builtin_bit_cast(unsigned int, f);
  u += 0x7fffu + ((u >> 16) & 1u);   // round-to-nearest-even
  return (unsigned short)(u >> 16);
}
__device__ __forceinline__ void bf2f2(unsigned int u, float& lo, float& hi) {
  lo = __builtin_bit_cast(float, u << 16);
  hi = __builtin_bit_cast(float, u & 0xffff0000u);
}

// async global->LDS, 16B per lane; lds dest must be wave-uniform base (lands at base + lane*16)
__device__ __forceinline__ void async16(const void* g, void* l) {
  __builtin_amdgcn_global_load_lds(
      (const __attribute__((address_space(1))) unsigned int*)g,
      (__attribute__((address_space(3))) unsigned int*)l, 16, 0, 0);
}

// ---- fp32 -> bf16 convert (vectorized) ----
__global__ __launch_bounds__(256) void k_cvt(const float4* __restrict__ in,
                                             ushort4* __restrict__ out, int n4) {
  int i = blockIdx.x * 256 + threadIdx.x;
  if (i < n4) {
    float4 v = in[i];
    ushort4 o;
    o.x = f2bf(v.x); o.y = f2bf(v.y); o.z = f2bf(v.z); o.w = f2bf(v.w);
    out[i] = o;
  }
}

// ---- per-dim query scale: Q_SCALE * softplus(per_dim_scale) ----
__global__ void k_qscale(const float* __restrict__ pds, float* __restrict__ qs) {
  int d = threadIdx.x;
  if (d < DD) {
    float x = pds[d];
    float sp = (x > 20.f) ? x : log1pf(expf(x));
    qs[d] = Q_SCALE_BASE * sp;
  }
}

// ---- rel_k = pos_emb @ w_rel.T  -> bf16 [CTXW][EE] ----
__global__ __launch_bounds__(256) void k_rel(const float* __restrict__ pos,
                                             const float* __restrict__ w_rel,
                                             unsigned short* __restrict__ rel16) {
  __shared__ unsigned short lp[12 * EE];
  const int t = threadIdx.x;
  const int p0 = blockIdx.y * 12;
  for (int i = t; i < 12 * EE / 4; i += 256) {
    float4 x = ((const float4*)(pos + (long)p0 * EE))[i];
    ushort4 o; o.x = f2bf(x.x); o.y = f2bf(x.y); o.z = f2bf(x.z); o.w = f2bf(x.w);
    ((ushort4*)lp)[i] = o;
  }
  __syncthreads();
  const int col = blockIdx.x * 128 + (t & 127);
  const int pg = t >> 7;  // 0 or 1 -> 6 p-rows each
  float acc[6] = {0.f, 0.f, 0.f, 0.f, 0.f, 0.f};
  const float* wr = w_rel + (long)col * EE;
  for (int e = 0; e < EE; e += 4) {
    float4 w4 = *(const float4*)&wr[e];
#pragma unroll
    for (int i = 0; i < 6; ++i) {
      const unsigned short* lpr = &lp[(pg * 6 + i) * EE + e];
      unsigned int u01 = *(const unsigned int*)lpr;
      unsigned int u23 = *(const unsigned int*)(lpr + 2);
      float a0, a1, a2, a3;
      bf2f2(u01, a0, a1); bf2f2(u23, a2, a3);
      acc[i] += w4.x * a0 + w4.y * a1 + w4.z * a2 + w4.w * a3;
    }
  }
#pragma unroll
  for (int i = 0; i < 6; ++i)
    rel16[(long)(p0 + pg * 6 + i) * EE + col] = f2bf(acc[i]);
}

// =====================================================================
// 256x256 8-phase bf16 MFMA GEMM (learn_hip m201 template, plain HIP)
// (unchanged from R2/R3 — MfmaUtil 44.5%, FETCH/WRITE near-ideal)
// =====================================================================

__device__ __forceinline__ void stage_half(const unsigned short* g0, long Kl,
                                           unsigned short* lhalf,
                                           int w, int rlo, int qz) {
  const unsigned short* s0 = g0 + (long)(w * 16 + rlo) * Kl + qz * 8;
  async16(s0,          lhalf + w * 1024);        // rows w*16 .. +7
  async16(s0 + 8 * Kl, lhalf + w * 1024 + 512);  // rows w*16+8 .. +15
}

__device__ __forceinline__ void tile4(
    unsigned short* AP, unsigned short* BP,        // current buffer (tile t)
    unsigned short* AQ, unsigned short* BQ,        // next buffer (tile t+1)
    const unsigned short* gAt, const unsigned short* gBt, long Kl,
    int t1, int t2, int w, int rlo, int qz,
    int aBase, int bBase, int sw0, int sw1, f32x4 (&acc)[8][4]) {
  s16x8 af[4], bf[4];

  // ---- P1: a(m0-3,ks0) + b(ks0); stage A-lo(t1) -> AQ ----
#pragma unroll
  for (int i = 0; i < 4; ++i) af[i] = *(const s16x8*)&AP[(aBase + 16 * i) * 64 + sw0];
#pragma unroll
  for (int j = 0; j < 4; ++j) bf[j] = *(const s16x8*)&BP[(bBase + 16 * j) * 64 + sw0];
  stage_half(gAt + (long)t1 * 64, Kl, AQ, w, rlo, qz);
  __builtin_amdgcn_s_barrier();
  __builtin_amdgcn_s_setprio(1);
#pragma unroll
  for (int i = 0; i < 4; ++i)
#pragma unroll
    for (int j = 0; j < 4; ++j)
      acc[i][j] = __builtin_amdgcn_mfma_f32_16x16x32_bf16(af[i], bf[j], acc[i][j], 0, 0, 0);
  __builtin_amdgcn_s_setprio(0);
  __builtin_amdgcn_s_barrier();

  // ---- P2: a(m4-7,ks0); stage A-hi(t1) -> AQ+8192 ----
#pragma unroll
  for (int i = 0; i < 4; ++i) af[i] = *(const s16x8*)&AP[(aBase + 64 + 16 * i) * 64 + sw0];
  stage_half(gAt + 128 * Kl + (long)t1 * 64, Kl, AQ + 8192, w, rlo, qz);
  __builtin_amdgcn_s_barrier();
  __builtin_amdgcn_s_setprio(1);
#pragma unroll
  for (int i = 0; i < 4; ++i)
#pragma unroll
    for (int j = 0; j < 4; ++j)
      acc[4 + i][j] = __builtin_amdgcn_mfma_f32_16x16x32_bf16(af[i], bf[j], acc[4 + i][j], 0, 0, 0);
  __builtin_amdgcn_s_setprio(0);
  __builtin_amdgcn_s_barrier();

  // ---- P3: a(m0-3,ks1) + b(ks1); no stage (cur.B still being read) ----
#pragma unroll
  for (int i = 0; i < 4; ++i) af[i] = *(const s16x8*)&AP[(aBase + 16 * i) * 64 + sw1];
#pragma unroll
  for (int j = 0; j < 4; ++j) bf[j] = *(const s16x8*)&BP[(bBase + 16 * j) * 64 + sw1];
  __builtin_amdgcn_s_barrier();
  __builtin_amdgcn_s_setprio(1);
#pragma unroll
  for (int i = 0; i < 4; ++i)
#pragma unroll
    for (int j = 0; j < 4; ++j)
      acc[i][j] = __builtin_amdgcn_mfma_f32_16x16x32_bf16(af[i], bf[j], acc[i][j], 0, 0, 0);
  __builtin_amdgcn_s_setprio(0);
  __builtin_amdgcn_s_barrier();

  // ---- P4: a(m4-7,ks1); stage B(t2) -> BP (freed after P3); counted vmcnt ----
#pragma unroll
  for (int i = 0; i < 4; ++i) af[i] = *(const s16x8*)&AP[(aBase + 64 + 16 * i) * 64 + sw1];
  stage_half(gBt + (long)t2 * 64, Kl, BP, w, rlo, qz);
  stage_half(gBt + 128 * Kl + (long)t2 * 64, Kl, BP + 8192, w, rlo, qz);
  // queue: B(t1) [P4 prev, 4] , A(t1) [P1/P2, 4] , B(t2) [now, 4]
  // vmcnt(4): retire B(t1)+A(t1) (>=2 phases old), keep B(t2) in flight.
  asm volatile("s_waitcnt vmcnt(4)" ::: "memory");
  __builtin_amdgcn_s_barrier();
  __builtin_amdgcn_s_setprio(1);
#pragma unroll
  for (int i = 0; i < 4; ++i)
#pragma unroll
    for (int j = 0; j < 4; ++j)
      acc[4 + i][j] = __builtin_amdgcn_mfma_f32_16x16x32_bf16(af[i], bf[j], acc[4 + i][j], 0, 0, 0);
  __builtin_amdgcn_s_setprio(0);
  __builtin_amdgcn_s_barrier();
}

__global__ __launch_bounds__(512, 2) void k_gemm256(
    const unsigned short* __restrict__ A, const unsigned short* __restrict__ Bt,
    void* __restrict__ Cv, int M, int N, int K, int gN,
    int mode, const float* __restrict__ qscale, int c_f32) {
  __shared__ unsigned short sm[65536];   // 128 KiB: A0|B0|A1|B1, 16384 shorts each

  const int tid = threadIdx.x;
  const int w = tid >> 6;
  const int lane = tid & 63;
  const int quad = lane >> 4;
  const int l16 = lane & 15;
  const int sw = l16 & 7;
  const int rlo = lane >> 3;             // staging: row-within-8 for this lane
  const int qz = (lane & 7) ^ rlo;       // staging: inverse-swizzled source granule

  // XCD-aware chunk (bijective, nwg % 8 == 0) + GM=4 grouped m-bands.
  const int nwg = gridDim.x;
  const int orig = blockIdx.x;
  const int qd = nwg >> 3;               // blocks per XCD chunk (multiple of gN)
  const int xcd = orig & 7;
  const int u = orig >> 3;               // position within chunk
  const int bandsz = 4 * gN;
  const int band = u / bandsz;
  const int rem = u - band * bandsz;
  const int mi = band * 4 + (rem & 3);
  const int ni = rem >> 2;
  const int mloc = qd / gN;              // m-tiles per chunk
  const int mt = xcd * mloc + mi;
  const int nt = ni;
  const long bm = (long)mt * 256, bn = (long)nt * 256;
  const long Kl = K;
  const unsigned short* gAt = A + bm * Kl;
  const unsigned short* gBt = Bt + bn * Kl;

  unsigned short* A0 = sm;
  unsigned short* B0 = sm + 16384;
  unsigned short* A1 = sm + 32768;
  unsigned short* B1 = sm + 49152;

  const int aBase = (w >> 2) * 128 + l16;            // wave M-panel row base
  const int bBase = (w & 3) * 64 + l16;              // wave N-panel row base
  const int sw0 = ((quad ^ sw) & 7) * 8;             // ks=0 swizzled granule offset (shorts)
  const int sw1 = (((4 | quad) ^ sw) & 7) * 8;       // ks=1

  f32x4 acc[8][4] = {};
  const int NT = K >> 6;                             // K-tiles of 64 (even)

  // ---- prologue: tile0 -> buf0; B(1) -> buf1.B; keep B(1) in flight ----
  stage_half(gAt,            Kl, A0,        w, rlo, qz);
  stage_half(gAt + 128 * Kl, Kl, A0 + 8192, w, rlo, qz);
  stage_half(gBt,            Kl, B0,        w, rlo, qz);
  stage_half(gBt + 128 * Kl, Kl, B0 + 8192, w, rlo, qz);
  stage_half(gBt + 64,            Kl, B1,        w, rlo, qz);
  stage_half(gBt + 128 * Kl + 64, Kl, B1 + 8192, w, rlo, qz);
  asm volatile("s_waitcnt vmcnt(4)" ::: "memory");   // tile0's 8 loads retired
  __builtin_amdgcn_s_barrier();

  for (int t = 0; t < NT; t += 2) {
    const int t1 = t + 1;
    const int t2 = (t + 2 == NT) ? 0 : t + 2;                 // wrap: dead re-stage, no OOB
    const int t3 = (t + 3 >= NT) ? t + 3 - NT : t + 3;
    tile4(A0, B0, A1, B1, gAt, gBt, Kl, t1, t2, w, rlo, qz, aBase, bBase, sw0, sw1, acc);
    tile4(A1, B1, A0, B0, gAt, gBt, Kl, t2, t3, w, rlo, qz, aBase, bBase, sw0, sw1, acc);
  }

  // ---- epilogue: drain, then LDS transpose for coalesced full-line stores.
  __syncthreads();

  const int wmq = (w >> 2) * 128;
  const int wnq = (w & 3) * 64;

  if (!c_f32) {
#pragma unroll
    for (int j = 0; j < 4; ++j) {
      const long col = bn + wnq + 16 * j + l16;
      float scale = 1.0f;
      if (mode == 3)
        scale = (col < 1536) ? qscale[col & (DD - 1)] : (col < 3072 ? K_SCALE_F : 1.0f);
      const int lc = wnq + 16 * j + l16;
#pragma unroll
      for (int i = 0; i < 8; ++i) {
        const int lr0 = wmq + 16 * i + quad * 4;
#pragma unroll
        for (int r = 0; r < 4; ++r) {
          const int lr = lr0 + r;
          const int gsw = (lc >> 3) ^ ((lr >> 2) & 7);
          sm[lr * 256 + gsw * 8 + (lc & 7)] = f2bf(acc[i][j][r] * scale);
        }
      }
    }
    __syncthreads();
#pragma unroll
    for (int k = 0; k < 16; ++k) {
      const int G = k * 512 + tid;            // 16B granule id, lanes consecutive
      const int row = G >> 5, gc = G & 31;
      const int gsw = gc ^ ((row >> 2) & 7);
      s16x8 vdat = *(const s16x8*)&sm[row * 256 + gsw * 8];
      *(s16x8*)&((unsigned short*)Cv)[(bm + row) * (long)N + bn + gc * 8] = vdat;
    }
  } else {
    float* Cf = (float*)sm;
#pragma unroll
    for (int h = 0; h < 2; ++h) {
      if ((wmq == 0) == (h == 0)) {   // waves owning this half write their acc
#pragma unroll
        for (int j = 0; j < 4; ++j) {
          const long col = bn + wnq + 16 * j + l16;
          float scale = 1.0f;
          if (mode == 3)
            scale = (col < 1536) ? qscale[col & (DD - 1)] : (col < 3072 ? K_SCALE_F : 1.0f);
          const int lc = wnq + 16 * j + l16;
#pragma unroll
          for (int i = 0; i < 8; ++i) {
            const int lr0 = 16 * i + quad * 4;
#pragma unroll
            for (int r = 0; r < 4; ++r) {
              const int lr = lr0 + r;
              const int gsw = (lc >> 2) ^ ((lr >> 2) & 7);
              Cf[lr * 256 + gsw * 4 + (lc & 3)] = acc[i][j][r] * scale;
            }
          }
        }
      }
      __syncthreads();
#pragma unroll
      for (int k = 0; k < 16; ++k) {
        const int G = k * 512 + tid;          // 16B granule (4 floats)
        const int row = G >> 6, gc = G & 63;
        const int gsw = gc ^ ((row >> 2) & 7);
        float4 vdat = *(const float4*)&Cf[row * 256 + gsw * 4];
        *(float4*)&((float*)Cv)[(bm + h * 128 + row) * (long)N + bn + gc * 4] = vdat;
      }
      __syncthreads();
    }
  }
}

// =====================================================================
// chunked local attention, G=4 chunks per block (latency-bound fix):
// grid (64, B, H), 512 threads = 8 waves, 2 blocks/CU (70.4 KB LDS).
// Per block: Q rows 48 (tokens 12*n0..+47), K/V window rows 0..63
// (token 12*n0-12+jj, zero outside [0,SEQ)), rel staged ONCE for the
// 4 chunks.  S_full[48][64] via 9 MFMA tiles (band coverage), BD[48][32]
// via 6 tiles; banded softmax; PV = W_band[48][64] x V[64][128] via
// 24 MFMA tiles.  All MFMA LDS reads use granule-XOR (T2) layouts;
// lvt adds ^(row>>3)&3 so the transpose-scatter writes spread banks.
// Phase overlays: lw over lk, sO over lk+lrel (dead after MFMA phase).
// =====================================================================
__global__ __launch_bounds__(512, 4) void k_attn(
    const unsigned short* __restrict__ qkv, const unsigned short* __restrict__ rel,
    unsigned short* __restrict__ attn_out, float* __restrict__ aw_out) {
  const int ng = blockIdx.x;
  const int b = blockIdx.y;
  const int h = blockIdx.z;
  const int t = threadIdx.x;
  const int wv = t >> 6;
  const int lane = t & 63;
  const int quad = lane >> 4;
  const int l16 = lane & 15;

  __shared__ __align__(16) char smem[72064];
  unsigned short* lq   = (unsigned short*)(smem);           // [48][128] swz
  unsigned short* lk   = (unsigned short*)(smem + 12288);   // [64][128] swz
  unsigned short* lrel = (unsigned short*)(smem + 28672);   // [32][128] swz (24 used)
  unsigned short* lvt  = (unsigned short*)(smem + 36864);   // [128][64] V^T dbl-swz
  float* sS  = (float*)(smem + 53248);                      // [48][65]
  float* sBD = (float*)(smem + 65728);                      // [48][33]
  unsigned short* lw = (unsigned short*)(smem + 12288);     // [48][64] swz (overlay lk)
  unsigned short* sO = (unsigned short*)(smem + 18432);     // [48][136] (overlay)
  __shared__ float smax[48], sinv[48];

  const int n0 = ng * 4;                         // first chunk of this block
  const long tokq0 = (long)b * SEQ + (long)n0 * CHK;
  const long hq = (long)h * DD;

  // ---- stage Q: 48 rows x 16 granules, granule-XOR dest ----
  for (int u = t; u < 48 * 16; u += 512) {
    int r = u >> 4, g = u & 15;
    uint4 x = *(const uint4*)&qkv[(tokq0 + r) * QKVP + hq + g * 8];
    *(uint4*)&lq[r * 128 + ((g ^ (r & 7)) * 8)] = x;
  }
  // ---- stage K rows + V transpose-scatter: 64 rows x 16 granules ----
  for (int u = t; u < 64 * 16; u += 512) {
    int r = u >> 4, g = u & 15;
    int s = n0 * CHK - 12 + r;
    uint4 kx = make_uint4(0, 0, 0, 0), vx = make_uint4(0, 0, 0, 0);
    if (s >= 0 && s < SEQ) {
      const unsigned short* base = &qkv[((long)b * SEQ + s) * QKVP + hq];
      kx = *(const uint4*)&base[1536 + g * 8];
      vx = *(const uint4*)&base[3072 + g * 8];
    }
    *(uint4*)&lk[r * 128 + ((g ^ (r & 7)) * 8)] = kx;
    unsigned short vs[8];
    *(uint4*)vs = vx;
#pragma unroll
    for (int i = 0; i < 8; ++i) {
      // row = 8g+i : row&7 = i, (row>>3)&3 = g&3 ; col jj = r
      int gr = (r >> 3) ^ i ^ (g & 3);
      lvt[(g * 8 + i) * 64 + gr * 8 + (r & 7)] = vs[i];
    }
  }
  // ---- stage rel: 32 rows (24 real, 8 zero) ----
  for (int u = t; u < 32 * 16; u += 512) {
    int r = u >> 4, g = u & 15;
    uint4 rx = make_uint4(0, 0, 0, 0);
    if (r < CTXW) rx = *(const uint4*)&rel[(long)r * EE + hq + g * 8];
    *(uint4*)&lrel[r * 128 + ((g ^ (r & 7)) * 8)] = rx;
  }
  __syncthreads();

  // ---- MFMA: 9 AC tiles + 6 BD tiles, split over 8 waves ----
  for (int pi = wv; pi < 15; pi += 8) {
    if (pi < 9) {
      const int mi = pi / 3;
      const int ni = pi % 3 + (mi == 2 ? 1 : 0);
      f32x4 c4 = {};
#pragma unroll
      for (int dc = 0; dc < 4; ++dc) {
        s16x8 a  = *(const s16x8*)&lq[(mi * 16 + l16) * 128 + (((dc * 4 + quad) ^ (l16 & 7)) * 8)];
        s16x8 bb = *(const s16x8*)&lk[(ni * 16 + l16) * 128 + (((dc * 4 + quad) ^ (l16 & 7)) * 8)];
        c4 = __builtin_amdgcn_mfma_f32_16x16x32_bf16(a, bb, c4, 0, 0, 0);
      }
#pragma unroll
      for (int r = 0; r < 4; ++r)
        sS[(mi * 16 + quad * 4 + r) * 65 + ni * 16 + l16] = c4[r];
    } else {
      const int q = pi - 9;
      const int mi = q >> 1, nj = q & 1;
      f32x4 c4 = {};
#pragma unroll
      for (int dc = 0; dc < 4; ++dc) {
        s16x8 a  = *(const s16x8*)&lq[(mi * 16 + l16) * 128 + (((dc * 4 + quad) ^ (l16 & 7)) * 8)];
        s16x8 bb = *(const s16x8*)&lrel[(nj * 16 + l16) * 128 + (((dc * 4 + quad) ^ (l16 & 7)) * 8)];
        c4 = __builtin_amdgcn_mfma_f32_16x16x32_bf16(a, bb, c4, 0, 0, 0);
      }
#pragma unroll
      for (int r = 0; r < 4; ++r)
        sBD[(mi * 16 + quad * 4 + r) * 33 + nj * 16 + l16] = c4[r];
    }
  }
  __syncthreads();

  // ---- rel-shift + softcap over the 48x24 band (in place in sS) ----
  for (int p = t; p < 48 * CTXW; p += 512) {
    int i = p / CTXW, j = p - i * CTXW;
    int cl = i / 12, r = i - cl * 12;
    float y;
    if (j >= r) y = sBD[i * 33 + (j - r)];
    else if (j == r - 1) y = 0.f;
    else y = sBD[(i - 1) * 33 + (j - r + CTXW + 1)];
    int jj = cl * 12 + j;
    float x = (sS[i * 65 + jj] + y) * 0.02f;
    x = fminf(fmaxf(x, -15.f), 15.f);
    float e2 = __expf(2.f * x);
    sS[i * 65 + jj] = 50.f * (e2 - 1.f) / (e2 + 1.f);   // 50*tanh(x)
  }
  __syncthreads();

  // ---- row max (48 rows) ----
  if (t < 48) {
    int base = t * 65 + (t / 12) * 12;
    float m = -3.0e38f;
#pragma unroll
    for (int j = 0; j < CTXW; ++j) m = fmaxf(m, sS[base + j]);
    smax[t] = m;
  }
  __syncthreads();

  // ---- exp (in place, band) ----
  for (int p = t; p < 48 * CTXW; p += 512) {
    int i = p / CTXW, j = p - i * CTXW;
    int jj = (i / 12) * 12 + j;
    sS[i * 65 + jj] = __expf(sS[i * 65 + jj] - smax[i]);
  }
  __syncthreads();

  // ---- row sum ----
  if (t < 48) {
    int base = t * 65 + (t / 12) * 12;
    float s = 0.f;
#pragma unroll
    for (int j = 0; j < CTXW; ++j) s += sS[base + j];
    sinv[t] = 1.f / s;
  }
  __syncthreads();

  // ---- pack W band -> lw[48][64] (zero outside band), write aw ----
  for (int p = t; p < 48 * 64; p += 512) {
    int i = p >> 6, jj = p & 63;
    int cl = i / 12;
    int j = jj - cl * 12;
    float wgt = 0.f;
    if (j >= 0 && j < CTXW) {
      wgt = sS[i * 65 + jj] * sinv[i];
      aw_out[((((long)b * HH + h) * NBLK + (n0 + cl)) * CHK + (i - cl * 12)) * CTXW + j] = wgt;
    }
    lw[i * 64 + (((jj >> 3) ^ (i & 7)) * 8) + (jj & 7)] = f2bf(wgt);
  }
  __syncthreads();

  // ---- PV: O[48][128] = W_band x V ; wave wv owns d-tile wv ----
  {
    const int rowv = wv * 16 + l16;
    const int vx3 = (rowv >> 3) & 3;
#pragma unroll
    for (int mi = 0; mi < 3; ++mi) {
      f32x4 o4 = {};
#pragma unroll
      for (int ks = 0; ks < 2; ++ks) {
        s16x8 a  = *(const s16x8*)&lw[(mi * 16 + l16) * 64 + (((ks * 4 + quad) ^ (l16 & 7)) * 8)];
        s16x8 bb = *(const s16x8*)&lvt[rowv * 64 + ((((ks * 4 + quad) ^ (l16 & 7)) ^ vx3) * 8)];
        o4 = __builtin_amdgcn_mfma_f32_16x16x32_bf16(a, bb, o4, 0, 0, 0);
      }
#pragma unroll
      for (int r = 0; r < 4; ++r)
        sO[(mi * 16 + quad * 4 + r) * 136 + wv * 16 + l16] = f2bf(o4[r]);
    }
  }
  __syncthreads();

  // ---- coalesced store of O: 48 rows x 16 granules ----
  for (int u = t; u < 48 * 16; u += 512) {
    int r = u >> 4, g = u & 15;
    uint4 x = *(const uint4*)&sO[r * 136 + g * 8];
    *(uint4*)&attn_out[(tokq0 + r) * EE + hq + g * 8] = x;
  }
}

extern "C" void kernel_launch(void* const* d_in, const int* in_sizes, int n_in,
                              void* d_out, int out_size, void* d_ws, size_t ws_size,
                              hipStream_t stream) {
  const float* hs     = (const float*)d_in[0];
  const float* pos    = (const float*)d_in[1];
  const float* w_q    = (const float*)d_in[2];
  const float* w_k    = (const float*)d_in[3];
  const float* w_v    = (const float*)d_in[4];
  const float* w_post = (const float*)d_in[5];
  const float* w_rel  = (const float*)d_in[6];
  const float* pds    = (const float*)d_in[7];

  char* ws = (char*)d_ws;
  const size_t TOKB = (size_t)MTOK * EE * 2;        // bytes per [MTOK,EE] bf16
  const size_t WB   = (size_t)EE * EE * 2;
  unsigned short* hs16   = (unsigned short*)(ws);
  unsigned short* qkv16  = (unsigned short*)(ws + TOKB);           // [MTOK][4608]
  unsigned short* wq16   = (unsigned short*)(ws + 4 * TOKB);       // wq|wk|wv contiguous
  unsigned short* wk16   = (unsigned short*)(ws + 4 * TOKB + WB);
  unsigned short* wv16   = (unsigned short*)(ws + 4 * TOKB + 2 * WB);
  unsigned short* wp16   = (unsigned short*)(ws + 4 * TOKB + 3 * WB);
  unsigned short* rel16  = (unsigned short*)(ws + 4 * TOKB + 4 * WB);
  float* qscale          = (float*)(ws + 4 * TOKB + 4 * WB + CTXW * EE * 2);
  unsigned short* attn16 = hs16;  // hs16 dead after qkv GEMM

  float* out = (float*)d_out;
  float* aw  = out + (size_t)MTOK * EE;

  // bf16 conversions
  k_cvt<<<36864, 256, 0, stream>>>((const float4*)hs, (ushort4*)hs16, MTOK * EE / 4);
  k_cvt<<<2304, 256, 0, stream>>>((const float4*)w_q, (ushort4*)wq16, EE * EE / 4);
  k_cvt<<<2304, 256, 0, stream>>>((const float4*)w_k, (ushort4*)wk16, EE * EE / 4);
  k_cvt<<<2304, 256, 0, stream>>>((const float4*)w_v, (ushort4*)wv16, EE * EE / 4);
  k_cvt<<<2304, 256, 0, stream>>>((const float4*)w_post, (ushort4*)wp16, EE * EE / 4);
  k_qscale<<<1, 128, 0, stream>>>(pds, qscale);
  k_rel<<<dim3(12, 2), 256, 0, stream>>>(pos, w_rel, rel16);

  // fused q|k|v projection: Bt = [wq;wk;wv] (contiguous), N=4608, scales in epilogue
  k_gemm256<<<dim3((MTOK / 256) * (QKVP / 256)), 512, 0, stream>>>(
      hs16, wq16, qkv16, MTOK, QKVP, EE, QKVP / 256, 3, qscale, 0);

  // attention: one block per (4 chunks, b, h)
  k_attn<<<dim3(NBLK / 4, NBATCH, HH), 512, 0, stream>>>(qkv16, rel16, attn16, aw);

  // output projection -> fp32 d_out
  k_gemm256<<<dim3((MTOK / 256) * (EE / 256)), 512, 0, stream>>>(
      attn16, wp16, out, MTOK, EE, EE, EE / 256, 0, nullptr, 1);
}